// Round 14
// baseline (126.443 us; speedup 1.0000x reference)
//
#include <hip/hip_runtime.h>

#define B_   4
#define L_   2048
#define D_   256
#define H_   8
#define DH_  32
#define MLP_ 1024
#define LOG2E 1.4426950408889634f

typedef __attribute__((ext_vector_type(8))) short  short8;
typedef __attribute__((ext_vector_type(4))) float  f32x4;
typedef __attribute__((ext_vector_type(2))) float  f32x2;
typedef unsigned long long ull;

union FragU { short8 v; struct { ull lo, hi; } q; unsigned u[4]; };
union SU { f32x4 v4; f32x2 v2[2]; };

__device__ __forceinline__ unsigned short f2bf(float f) {
  unsigned u = __float_as_uint(f);
  u += 0x7fffu + ((u >> 16) & 1u);
  return (unsigned short)(u >> 16);
}

__device__ __forceinline__ ull pack4(float a, float b, float c, float d) {
  return (ull)f2bf(a) | ((ull)f2bf(b) << 16) | ((ull)f2bf(c) << 32) | ((ull)f2bf(d) << 48);
}

__device__ __forceinline__ unsigned cvt_pk_bf16(float lo, float hi) {
  unsigned r;
  asm("v_cvt_pk_bf16_f32 %0, %1, %2" : "=v"(r) : "v"(lo), "v"(hi));
  return r;
}

// packed f32 add (legal VOP3P on gfx950; pk_max is NOT)
__device__ __forceinline__ f32x2 pk_add(f32x2 a, f32x2 b) {
  f32x2 r; asm("v_pk_add_f32 %0, %1, %2" : "=v"(r) : "v"(a), "v"(b)); return r;
}

__device__ __forceinline__ float fexp2(float x) {
#if __has_builtin(__builtin_amdgcn_exp2f)
  return __builtin_amdgcn_exp2f(x);
#else
  return exp2f(x);
#endif
}

#define GLL16(gp, lp) __builtin_amdgcn_global_load_lds( \
    (const __attribute__((address_space(1))) void*)(gp), \
    (__attribute__((address_space(3))) void*)(lp), 16, 0, 0)

// ---------------- elementwise converts: x, mask, far-field tables ----------------
__global__ void prep_w(const float* __restrict__ x,
                       const int* __restrict__ mask, const float* __restrict__ relb,
                       unsigned short* __restrict__ xb,
                       float* __restrict__ maskf,
                       float* __restrict__ mlo, float* __restrict__ mhi) {
  const int i = blockIdx.x * 256 + threadIdx.x;
  if (i < 524288) {            // x: 2,097,152 floats, 4 per thread
    const float4 v = *(const float4*)(x + (size_t)i * 4);
    *(ull*)(xb + (size_t)i * 4) = pack4(v.x, v.y, v.z, v.w);
  } else if (i < 532480) {     // raw mask -> additive float [B,L]
    const int j = i - 524288;
    maskf[j] = mask[j] ? -1e9f : 0.f;
  } else {                     // pre-biased far-field tables [B*H][L], lo and hi
    const int j2 = i - 532480;
    const int t = j2 >> 16, idx = j2 & 65535;
    const int bh = idx >> 11, j = idx & 2047;
    const int bq = bh >> 3, h = bh & 7;
    const float base = mask[bq * L_ + j] ? -1e9f : 0.f;
    const float bias = relb[(t ? 32 * H_ : 0) + h] * LOG2E;
    (t ? mhi : mlo)[idx] = base + bias;
  }
}

// ---------------- LDS-tiled weight transposes (coalesced both sides) ----------------
// 768 tiles of 32x32: Wqkv 8x24, Wo 8x8, W1 8x32, W2 32x8.
__launch_bounds__(256)
__global__ void prep_t(const float* __restrict__ Wqkv, const float* __restrict__ Wo,
                       const float* __restrict__ W1, const float* __restrict__ W2,
                       unsigned short* __restrict__ wqkvt, unsigned short* __restrict__ wot,
                       unsigned short* __restrict__ w1t, unsigned short* __restrict__ w2t) {
  __shared__ float tile[32][33];
  const int bid = blockIdx.x;
  const float* src; unsigned short* dst; int R, C, tr, tc;
  if (bid < 192)      { src = Wqkv; dst = wqkvt; R = 256;  C = 768;  tr = bid / 24;          tc = bid % 24; }
  else if (bid < 256) { src = Wo;   dst = wot;   R = 256;  C = 256;  tr = (bid - 192) >> 3;  tc = (bid - 192) & 7; }
  else if (bid < 512) { src = W1;   dst = w1t;   R = 256;  C = 1024; tr = (bid - 256) >> 5;  tc = (bid - 256) & 31; }
  else                { src = W2;   dst = w2t;   R = 1024; C = 256;  tr = (bid - 512) >> 3;  tc = (bid - 512) & 7; }
  const int tx = threadIdx.x & 31, ty = threadIdx.x >> 5;   // ty 0..7
#pragma unroll
  for (int i = 0; i < 4; ++i) {
    const int r = tr * 32 + ty + i * 8;
    tile[ty + i * 8][tx] = src[(size_t)r * C + tc * 32 + tx];
  }
  __syncthreads();
#pragma unroll
  for (int i = 0; i < 4; ++i) {
    const int c = tc * 32 + ty + i * 8;
    dst[(size_t)c * R + tr * 32 + tx] = f2bf(tile[tx][ty + i * 8]);
  }
}

// ---------------- GEMM (dbuf, counted vmcnt, XCD-swizzled 1D grid) ----------------
template <int MODE, int TM, int TN, int NBX, int BYG>
__launch_bounds__(256)
__global__ void gemm_k(const unsigned short* __restrict__ A,
                       const unsigned short* __restrict__ Bt,
                       const float* __restrict__ bias,
                       unsigned short* __restrict__ outb0,
                       unsigned short* __restrict__ outb1,
                       unsigned short* __restrict__ outb2,
                       int K)
{
  constexpr int MI = TM / 32, NI = TN / 32;
  __shared__ alignas(16) unsigned short As[2][TM * 64];
  __shared__ alignas(16) unsigned short Bs[2][TN * 64];
  const int tid  = threadIdx.x;
  const int lane = tid & 63, wv = tid >> 6;
  const int wr = wv >> 1, wc = wv & 1;
  const int lr = lane & 15, g = lane >> 4;
  const int bid = blockIdx.x;
  const int xcd = bid & 7, ii = bid >> 3;
  const int by = xcd * BYG + ii / NBX;
  const int bx = ii % NBX;
  const int m0 = by * TM, n0 = bx * TN;
  const int l8 = lane >> 3, jj = lane & 7;

  auto stage = [&](int buf, int k0) {
#pragma unroll
    for (int i = 0; i < MI; ++i) {
      const int row = i * 32 + wv * 8 + l8;
      GLL16(A + (size_t)(m0 + row) * K + k0 + ((jj ^ (row & 7)) * 8),
            &As[buf][i * 2048 + wv * 512]);
    }
#pragma unroll
    for (int i = 0; i < NI; ++i) {
      const int row = i * 32 + wv * 8 + l8;
      GLL16(Bt + (size_t)(n0 + row) * K + k0 + ((jj ^ (row & 7)) * 8),
            &Bs[buf][i * 2048 + wv * 512]);
    }
  };

  f32x4 acc[MI][NI];
#pragma unroll
  for (int i = 0; i < MI; ++i)
#pragma unroll
    for (int j = 0; j < NI; ++j) acc[i][j] = (f32x4)(0.f);

  stage(0, 0);
  for (int k0 = 0; k0 < K; k0 += 64) {
    const int cur = (k0 >> 6) & 1;
    if (k0 + 64 < K) {
      stage(cur ^ 1, k0 + 64);
      asm volatile("s_waitcnt vmcnt(%0)" :: "n"(MI + NI) : "memory");
    } else {
      asm volatile("s_waitcnt vmcnt(0)" ::: "memory");
    }
    __builtin_amdgcn_sched_barrier(0);
    __builtin_amdgcn_s_barrier();
#pragma unroll
    for (int kk = 0; kk < 2; ++kk) {
      FragU af[MI], bf[NI];
#pragma unroll
      for (int mi = 0; mi < MI; ++mi) {
        const int row = wr * (TM / 2) + mi * 16 + lr;
        const int sw = (row & 7) << 3;
        af[mi].q.lo = *(const ull*)&As[cur][row * 64 + ((kk * 32 + 4 * g) ^ sw)];
        af[mi].q.hi = *(const ull*)&As[cur][row * 64 + ((kk * 32 + 16 + 4 * g) ^ sw)];
      }
#pragma unroll
      for (int ni = 0; ni < NI; ++ni) {
        const int row = wc * (TN / 2) + ni * 16 + lr;
        const int sw = (row & 7) << 3;
        bf[ni].q.lo = *(const ull*)&Bs[cur][row * 64 + ((kk * 32 + 4 * g) ^ sw)];
        bf[ni].q.hi = *(const ull*)&Bs[cur][row * 64 + ((kk * 32 + 16 + 4 * g) ^ sw)];
      }
#pragma unroll
      for (int mi = 0; mi < MI; ++mi)
#pragma unroll
        for (int ni = 0; ni < NI; ++ni)
          acc[mi][ni] = __builtin_amdgcn_mfma_f32_16x16x32_bf16(af[mi].v, bf[ni].v, acc[mi][ni], 0, 0, 0);
    }
    asm volatile("s_waitcnt lgkmcnt(0)" ::: "memory");
    __builtin_amdgcn_sched_barrier(0);
    __builtin_amdgcn_s_barrier();
  }

#pragma unroll
  for (int mi = 0; mi < MI; ++mi) {
#pragma unroll
    for (int ni = 0; ni < NI; ++ni) {
      const int n = n0 + wc * (TN / 2) + ni * 16 + lr;
      const float bv = bias[n];
#pragma unroll
      for (int r = 0; r < 4; ++r) {
        const int m = m0 + wr * (TM / 2) + mi * 16 + 4 * g + r;
        float val = acc[mi][ni][r] + bv;
        if constexpr (MODE == 0) {
          const int s = n >> 8, hh = (n >> 5) & 7, dh = n & 31;
          const int bb = m >> 11, l = m & (L_ - 1);
          if (s == 0) {
            outb0[((size_t)(bb * H_ + hh) * L_ + l) * DH_ + dh] =
                f2bf(val * (0.17677669529663687f * LOG2E));
          } else if (s == 1) {
            outb1[((size_t)(bb * H_ + hh) * L_ + l) * DH_ + dh] = f2bf(val);
          } else {
            outb2[((size_t)(bb * H_ + hh) * DH_ + dh) * L_ + l] = f2bf(val);
          }
        } else {
          outb0[(size_t)m * MLP_ + n] = f2bf(fmaxf(val, 0.f));
        }
      }
    }
  }
}

// ---------------- fused GEMM + residual + LayerNorm (LDS-staged, TN=256, TM=16) ----------------
template <bool WRITE_BF>
__launch_bounds__(512)
__global__ void gemmln_k(const unsigned short* __restrict__ A,
                         const unsigned short* __restrict__ Bt,
                         const float* __restrict__ bias,
                         const float* __restrict__ resid,
                         const float* __restrict__ lng,
                         const float* __restrict__ lnb,
                         float* __restrict__ outf,
                         unsigned short* __restrict__ outb,
                         int K)
{
  __shared__ alignas(16) unsigned short As[2][16 * 64];
  __shared__ alignas(16) unsigned short Bs[2][256 * 64];
  __shared__ float rsum[8][16], rsq[8][16], rmu[16], rrstd[16];
  const int tid  = threadIdx.x;
  const int lane = tid & 63, wv = tid >> 6;
  const int lr = lane & 15, g = lane >> 4;
  const int m0 = blockIdx.x * 16;
  const int l8 = lane >> 3, jj = lane & 7;

  auto stage = [&](int buf, int k0) {
    if (wv < 2) {
      const int row = wv * 8 + l8;
      GLL16(A + (size_t)(m0 + row) * K + k0 + ((jj ^ (row & 7)) * 8),
            &As[buf][wv * 512]);
    }
#pragma unroll
    for (int i = 0; i < 4; ++i) {
      const int n = i * 64 + wv * 8 + l8;
      GLL16(Bt + (size_t)n * K + k0 + ((jj ^ (n & 7)) * 8),
            &Bs[buf][i * 4096 + wv * 512]);
    }
  };

  f32x4 acc[2];
  acc[0] = (f32x4)(0.f); acc[1] = (f32x4)(0.f);

  stage(0, 0);
  for (int k0 = 0; k0 < K; k0 += 64) {
    const int cur = (k0 >> 6) & 1;
    if (k0 + 64 < K) {
      stage(cur ^ 1, k0 + 64);
      asm volatile("s_waitcnt vmcnt(4)" ::: "memory");
    } else {
      asm volatile("s_waitcnt vmcnt(0)" ::: "memory");
    }
    __builtin_amdgcn_sched_barrier(0);
    __builtin_amdgcn_s_barrier();
#pragma unroll
    for (int kk = 0; kk < 2; ++kk) {
      FragU af, bf[2];
      {
        const int sw = (lr & 7) << 3;
        af.q.lo = *(const ull*)&As[cur][lr * 64 + ((kk * 32 + 4 * g) ^ sw)];
        af.q.hi = *(const ull*)&As[cur][lr * 64 + ((kk * 32 + 16 + 4 * g) ^ sw)];
      }
#pragma unroll
      for (int ni = 0; ni < 2; ++ni) {
        const int row = wv * 32 + ni * 16 + lr;
        const int sw = (row & 7) << 3;
        bf[ni].q.lo = *(const ull*)&Bs[cur][row * 64 + ((kk * 32 + 4 * g) ^ sw)];
        bf[ni].q.hi = *(const ull*)&Bs[cur][row * 64 + ((kk * 32 + 16 + 4 * g) ^ sw)];
      }
#pragma unroll
      for (int ni = 0; ni < 2; ++ni)
        acc[ni] = __builtin_amdgcn_mfma_f32_16x16x32_bf16(af.v, bf[ni].v, acc[ni], 0, 0, 0);
    }
    asm volatile("s_waitcnt lgkmcnt(0)" ::: "memory");
    __builtin_amdgcn_sched_barrier(0);
    __builtin_amdgcn_s_barrier();
  }

  float g2[2], b2[2], bias2[2];
  int col[2];
#pragma unroll
  for (int ni = 0; ni < 2; ++ni) {
    col[ni] = wv * 32 + ni * 16 + lr;
    g2[ni] = lng[col[ni]]; b2[ni] = lnb[col[ni]]; bias2[ni] = bias[col[ni]];
  }
  float vals[2][4];
#pragma unroll
  for (int r = 0; r < 4; ++r) {
    const int row = 4 * g + r;
    float s = 0.f, q = 0.f;
#pragma unroll
    for (int ni = 0; ni < 2; ++ni) {
      float v = acc[ni][r] + bias2[ni] + resid[(size_t)(m0 + row) * D_ + col[ni]];
      vals[ni][r] = v; s += v; q += v * v;
    }
#pragma unroll
    for (int off = 1; off < 16; off <<= 1) {
      s += __shfl_xor(s, off); q += __shfl_xor(q, off);
    }
    if (lr == 0) { rsum[wv][row] = s; rsq[wv][row] = q; }
  }
  __syncthreads();
  if (tid < 16) {
    float s = 0.f, q = 0.f;
#pragma unroll
    for (int w = 0; w < 8; ++w) { s += rsum[w][tid]; q += rsq[w][tid]; }
    const float mu = s * (1.f / D_);
    rmu[tid] = mu;
    rrstd[tid] = rsqrtf(q * (1.f / D_) - mu * mu + 1e-5f);
  }
  __syncthreads();
#pragma unroll
  for (int r = 0; r < 4; ++r) {
    const int row = 4 * g + r;
    const float mu = rmu[row], rs = rrstd[row];
#pragma unroll
    for (int ni = 0; ni < 2; ++ni) {
      const float o = (vals[ni][r] - mu) * rs * g2[ni] + b2[ni];
      const size_t idx = (size_t)(m0 + row) * D_ + col[ni];
      outf[idx] = o;
      if constexpr (WRITE_BF) outb[idx] = f2bf(o);
    }
  }
}

// ---------------- flash attention: 128 q/block (8 waves x 16 q), KV chunk 128,
// K fragments DIRECT from global (L1-resident) with one-chunk-ahead register
// prefetch (16B frags via shared sigma=8g+i on Q and K); V dbuf in LDS via gll16;
// counted vmcnt(8) at barrier keeps K prefetch in flight. Max-free softmax,
// pre-biased far-field tables, XCD-swizzled 1D grid. ----------------
__launch_bounds__(512)
__global__ void attn_k(const unsigned short* __restrict__ qb,
                       const unsigned short* __restrict__ kp,
                       const unsigned short* __restrict__ vT,
                       const float* __restrict__ maskf,
                       const float* __restrict__ mlo,
                       const float* __restrict__ mhi,
                       const float* __restrict__ relb,
                       unsigned short* __restrict__ aout)
{
  __shared__ alignas(16) unsigned short Vs[2][32 * 128];   // XOR-swizzled
  __shared__ alignas(16) float biasv[36];
  const int tid = threadIdx.x;
  const int lane = tid & 63, wv = tid >> 6;                // wv in 0..7
  const int lr = lane & 15, g = lane >> 4;
  // XCD-aware decode: 512 blocks = 8 xcd * 4 bh * 16 qblk (bijective)
  const int bid = blockIdx.x;
  const int ii = bid >> 3;
  const int bh = (bid & 7) * 4 + (ii >> 4);
  const int qblk = ii & 15;
  const int b = bh >> 3, h = bh & 7;
  const size_t bhoff = (size_t)bh * (L_ * DH_);
  if (tid < 33) biasv[tid] = relb[tid * H_ + h] * LOG2E;
  const int qw0 = qblk * 128 + wv * 16;

  FragU qf;
  qf.v = *(const short8*)(qb + bhoff + (size_t)(qw0 + lr) * DH_ + 8 * g);

  f32x4 O0 = (f32x4)(0.f), O1 = (f32x4)(0.f);
  f32x2 ssum2 = {0.f, 0.f};
  const f32x4 z4 = (f32x4)(0.f);
  const unsigned short* kb0 = kp + bhoff + (size_t)lr * DH_ + 8 * g;  // per-lane K base
  const float* mtl = mlo + (size_t)bh * L_ + 4 * g;
  const float* mth = mhi + (size_t)bh * L_ + 4 * g;
  const float* mbn = maskf + (size_t)b * L_ + 4 * g;

  // prologue: K frags chunk 0 -> regs; V chunk 0 -> Vs[0]
  FragU kreg[8];                                           // [st*4+jt], static-indexed
#pragma unroll
  for (int st = 0; st < 2; ++st)
#pragma unroll
    for (int jt = 0; jt < 4; ++jt)
      kreg[st * 4 + jt].v = *(const short8*)(kb0 + (size_t)(st * 64 + jt * 16) * DH_);
  {
    const int d = wv * 4 + (lane >> 4);
    GLL16(vT + ((size_t)bh * DH_ + d) * L_ + (((lane & 15) * 8) ^ ((d & 7) * 8)),
          &Vs[0][wv * 512]);
    asm volatile("s_waitcnt vmcnt(0) lgkmcnt(0)" ::: "memory");
    __builtin_amdgcn_s_barrier();
  }

#pragma unroll 2
  for (int ch = 0; ch < 16; ++ch) {
    const int cur = ch & 1, nxt = cur ^ 1;
    const int kv = ch * 128;
    const bool more = ch < 15;
    if (more) {   // V prefetch for chunk ch+1 into the inactive buffer
      const int d = wv * 4 + (lane >> 4);
      GLL16(vT + ((size_t)bh * DH_ + d) * L_ + kv + 128 + (((lane & 15) * 8) ^ ((d & 7) * 8)),
            &Vs[nxt][wv * 512]);
    }

    // QK: 8 MFMAs from register-resident K frags
    SU sT[2][4];
#pragma unroll
    for (int st = 0; st < 2; ++st)
#pragma unroll
      for (int jt = 0; jt < 4; ++jt)
        sT[st][jt].v4 = __builtin_amdgcn_mfma_f32_16x16x32_bf16(kreg[st * 4 + jt].v, qf.v, z4, 0, 0, 0);

    // refill K regs for chunk ch+1 (L1 hits; ~full chunk of compute to land)
    if (more) {
#pragma unroll
      for (int st = 0; st < 2; ++st)
#pragma unroll
        for (int jt = 0; jt < 4; ++jt)
          kreg[st * 4 + jt].v =
              *(const short8*)(kb0 + (size_t)(kv + 128 + st * 64 + jt * 16) * DH_);
    }

#pragma unroll
    for (int st = 0; st < 2; ++st) {
      const int j0 = kv + st * 64;
      const int dlt = j0 - qw0;
      if (dlt >= 32 || dlt <= -80) {          // far field: pre-biased table
        const float* mt = (dlt > 0) ? mth : mtl;
#pragma unroll
        for (int jt = 0; jt < 4; ++jt) {
          SU mk; mk.v4 = *(const f32x4*)(mt + j0 + jt * 16);
          sT[st][jt].v2[0] = pk_add(sT[st][jt].v2[0], mk.v2[0]);
          sT[st][jt].v2[1] = pk_add(sT[st][jt].v2[1], mk.v2[1]);
        }
      } else {                                 // near field (2 of 32 sub-tiles)
#pragma unroll
        for (int jt = 0; jt < 4; ++jt)
#pragma unroll
          for (int r = 0; r < 4; ++r) {
            int rel = j0 + jt * 16 + 4 * g + r - (qw0 + lr);
            rel = rel < -16 ? -16 : (rel > 16 ? 16 : rel);
            sT[st][jt].v4[r] += biasv[rel + 16] + mbn[j0 + jt * 16 + r];
          }
      }
      // max-free: p = exp2(s) directly (masked -> 0)
#pragma unroll
      for (int jt = 0; jt < 4; ++jt)
#pragma unroll
        for (int r = 0; r < 4; ++r)
          sT[st][jt].v4[r] = fexp2(sT[st][jt].v4[r]);
      // packed partial-sum accumulate
      const f32x2 s01 = pk_add(sT[st][0].v2[0], sT[st][0].v2[1]);
      const f32x2 s23 = pk_add(sT[st][1].v2[0], sT[st][1].v2[1]);
      const f32x2 s45 = pk_add(sT[st][2].v2[0], sT[st][2].v2[1]);
      const f32x2 s67 = pk_add(sT[st][3].v2[0], sT[st][3].v2[1]);
      ssum2 = pk_add(ssum2, pk_add(pk_add(s01, s23), pk_add(s45, s67)));

      FragU a0, a1;
      a0.u[0] = cvt_pk_bf16(sT[st][0].v4[0], sT[st][0].v4[1]);
      a0.u[1] = cvt_pk_bf16(sT[st][0].v4[2], sT[st][0].v4[3]);
      a0.u[2] = cvt_pk_bf16(sT[st][1].v4[0], sT[st][1].v4[1]);
      a0.u[3] = cvt_pk_bf16(sT[st][1].v4[2], sT[st][1].v4[3]);
      a1.u[0] = cvt_pk_bf16(sT[st][2].v4[0], sT[st][2].v4[1]);
      a1.u[1] = cvt_pk_bf16(sT[st][2].v4[2], sT[st][2].v4[3]);
      a1.u[2] = cvt_pk_bf16(sT[st][3].v4[0], sT[st][3].v4[1]);
      a1.u[3] = cvt_pk_bf16(sT[st][3].v4[2], sT[st][3].v4[3]);

      FragU vf00, vf01, vf10, vf11;
#pragma unroll
      for (int dt = 0; dt < 2; ++dt) {
        const int row = dt * 16 + lr;
        const int sw = (row & 7) << 3;
        FragU v0, v1;
        v0.q.lo = *(const ull*)&Vs[cur][row * 128 + ((st * 64 + 4 * g) ^ sw)];
        v0.q.hi = *(const ull*)&Vs[cur][row * 128 + ((st * 64 + 16 + 4 * g) ^ sw)];
        v1.q.lo = *(const ull*)&Vs[cur][row * 128 + ((st * 64 + 32 + 4 * g) ^ sw)];
        v1.q.hi = *(const ull*)&Vs[cur][row * 128 + ((st * 64 + 48 + 4 * g) ^ sw)];
        if (dt == 0) { vf00 = v0; vf01 = v1; } else { vf10 = v0; vf11 = v1; }
      }
      O0 = __builtin_amdgcn_mfma_f32_16x16x32_bf16(a0.v, vf00.v, O0, 0, 0, 0);
      O0 = __builtin_amdgcn_mfma_f32_16x16x32_bf16(a1.v, vf01.v, O0, 0, 0, 0);
      O1 = __builtin_amdgcn_mfma_f32_16x16x32_bf16(a0.v, vf10.v, O1, 0, 0, 0);
      O1 = __builtin_amdgcn_mfma_f32_16x16x32_bf16(a1.v, vf11.v, O1, 0, 0, 0);
    }

    if (more) {
      // counted wait: oldest outstanding is this chunk's gll16 (issued first);
      // the 8 K-prefetch loads stay in flight across the barrier.
      asm volatile("s_waitcnt vmcnt(8) lgkmcnt(0)" ::: "memory");
      __builtin_amdgcn_sched_barrier(0);
      __builtin_amdgcn_s_barrier();
    }
  }

  // epilogue: reduce denominator, write O
  float ssum = ssum2[0] + ssum2[1];
  ssum += __shfl_xor(ssum, 16);
  ssum += __shfl_xor(ssum, 32);
#pragma unroll
  for (int r = 0; r < 4; ++r) {
    const float sden = __shfl(ssum, 4 * g + r);
    const float inv = 1.f / sden;
    const int qo = qw0 + 4 * g + r;
    unsigned short* orow = aout + ((size_t)(b * L_ + qo)) * D_ + h * DH_;
    orow[lr]      = f2bf(O0[r] * inv);
    orow[16 + lr] = f2bf(O1[r] * inv);
  }
}

// ---------------- launch ----------------
extern "C" void kernel_launch(void* const* d_in, const int* in_sizes, int n_in,
                              void* d_out, int out_size, void* d_ws, size_t ws_size,
                              hipStream_t stream) {
  (void)in_sizes; (void)n_in; (void)out_size; (void)ws_size;
  const float* x    = (const float*)d_in[0];
  const int*   mask = (const int*)d_in[1];
  const float* Wqkv = (const float*)d_in[2];
  const float* bqkv = (const float*)d_in[3];
  const float* Wo   = (const float*)d_in[4];
  const float* bo   = (const float*)d_in[5];
  const float* ln1g = (const float*)d_in[6];
  const float* ln1b = (const float*)d_in[7];
  const float* W1   = (const float*)d_in[8];
  const float* b1   = (const float*)d_in[9];
  const float* W2   = (const float*)d_in[10];
  const float* b2   = (const float*)d_in[11];
  const float* ln2g = (const float*)d_in[12];
  const float* ln2b = (const float*)d_in[13];
  const float* relb = (const float*)d_in[14];

  size_t off = 0;
  char* wsb = (char*)d_ws;
  auto carve = [&](size_t bytes) -> void* {
    void* p = wsb + off;
    off += (bytes + 255) & ~(size_t)255;
    return p;
  };
  const size_t tokb = (size_t)B_ * L_;
  unsigned short* xb    = (unsigned short*)carve(tokb * D_ * 2);
  unsigned short* qbuf  = (unsigned short*)carve(tokb * D_ * 2);
  unsigned short* kbuf  = (unsigned short*)carve(tokb * D_ * 2);
  unsigned short* vTb   = (unsigned short*)carve(tokb * D_ * 2);
  unsigned short* attnb = (unsigned short*)carve(tokb * D_ * 2);
  unsigned short* wqkvt = (unsigned short*)carve((size_t)3 * D_ * D_ * 2);
  unsigned short* wot   = (unsigned short*)carve((size_t)D_ * D_ * 2);
  unsigned short* w1t   = (unsigned short*)carve((size_t)D_ * MLP_ * 2);
  unsigned short* w2t   = (unsigned short*)carve((size_t)D_ * MLP_ * 2);
  float*          x1    = (float*)carve(tokb * D_ * 4);
  unsigned short* x1b   = (unsigned short*)carve(tokb * D_ * 2);
  unsigned short* hbuf  = (unsigned short*)carve(tokb * MLP_ * 2);
  float*          maskfb = (float*)carve(tokb * 4);
  float*          mlob  = (float*)carve((size_t)B_ * H_ * L_ * 4);
  float*          mhib  = (float*)carve((size_t)B_ * H_ * L_ * 4);

  prep_w<<<2592, 256, 0, stream>>>(x, mask, relb, xb, maskfb, mlob, mhib);
  prep_t<<<768, 256, 0, stream>>>(Wqkv, Wo, W1, W2, wqkvt, wot, w1t, w2t);

  // qkv: nbx=6, nby=128 -> 768 blocks = 6*8*16
  gemm_k<0, 64, 128, 6, 16><<<768, 256, 0, stream>>>(
      xb, wqkvt, bqkv, qbuf, kbuf, vTb, D_);
  // attn: 512 blocks = 8 xcd * 4 bh * 16 qblk, 128 q/block
  attn_k<<<512, 512, 0, stream>>>(
      qbuf, kbuf, vTb, maskfb, mlob, mhib, relb, attnb);
  gemmln_k<true><<<tokb / 16, 512, 0, stream>>>(
      attnb, wot, bo, x, ln1g, ln1b, x1, x1b, D_);
  // mlp1: nbx=8, nby=128 -> 1024 blocks = 8*8*16
  gemm_k<2, 64, 128, 8, 16><<<1024, 256, 0, stream>>>(
      x1b, w1t, b1, hbuf, nullptr, nullptr, D_);
  gemmln_k<false><<<tokb / 16, 512, 0, stream>>>(
      hbuf, w2t, b2, x1, ln2g, ln2b, (float*)d_out, nullptr, MLP_);
}

// Round 15
// 110.744 us; speedup vs baseline: 1.1418x; 1.1418x over previous
//
#include <hip/hip_runtime.h>

#define B_   4
#define L_   2048
#define D_   256
#define H_   8
#define DH_  32
#define MLP_ 1024
#define LOG2E 1.4426950408889634f

typedef __attribute__((ext_vector_type(8))) short  short8;
typedef __attribute__((ext_vector_type(4))) float  f32x4;
typedef __attribute__((ext_vector_type(2))) float  f32x2;
typedef unsigned long long ull;

union FragU { short8 v; struct { ull lo, hi; } q; unsigned u[4]; };
union SU { f32x4 v4; f32x2 v2[2]; };

__device__ __forceinline__ unsigned short f2bf(float f) {
  unsigned u = __float_as_uint(f);
  u += 0x7fffu + ((u >> 16) & 1u);
  return (unsigned short)(u >> 16);
}

__device__ __forceinline__ ull pack4(float a, float b, float c, float d) {
  return (ull)f2bf(a) | ((ull)f2bf(b) << 16) | ((ull)f2bf(c) << 32) | ((ull)f2bf(d) << 48);
}

__device__ __forceinline__ unsigned cvt_pk_bf16(float lo, float hi) {
  unsigned r;
  asm("v_cvt_pk_bf16_f32 %0, %1, %2" : "=v"(r) : "v"(lo), "v"(hi));
  return r;
}

// packed f32 add (legal VOP3P on gfx950; pk_max is NOT)
__device__ __forceinline__ f32x2 pk_add(f32x2 a, f32x2 b) {
  f32x2 r; asm("v_pk_add_f32 %0, %1, %2" : "=v"(r) : "v"(a), "v"(b)); return r;
}

__device__ __forceinline__ float fexp2(float x) {
#if __has_builtin(__builtin_amdgcn_exp2f)
  return __builtin_amdgcn_exp2f(x);
#else
  return exp2f(x);
#endif
}

#define GLL16(gp, lp) __builtin_amdgcn_global_load_lds( \
    (const __attribute__((address_space(1))) void*)(gp), \
    (__attribute__((address_space(3))) void*)(lp), 16, 0, 0)

// ---------------- elementwise converts: x, mask, far-field tables ----------------
__global__ void prep_w(const float* __restrict__ x,
                       const int* __restrict__ mask, const float* __restrict__ relb,
                       unsigned short* __restrict__ xb,
                       float* __restrict__ maskf,
                       float* __restrict__ mlo, float* __restrict__ mhi) {
  const int i = blockIdx.x * 256 + threadIdx.x;
  if (i < 524288) {            // x: 2,097,152 floats, 4 per thread
    const float4 v = *(const float4*)(x + (size_t)i * 4);
    *(ull*)(xb + (size_t)i * 4) = pack4(v.x, v.y, v.z, v.w);
  } else if (i < 532480) {     // raw mask -> additive float [B,L]
    const int j = i - 524288;
    maskf[j] = mask[j] ? -1e9f : 0.f;
  } else {                     // pre-biased far-field tables [B*H][L], lo and hi
    const int j2 = i - 532480;
    const int t = j2 >> 16, idx = j2 & 65535;
    const int bh = idx >> 11, j = idx & 2047;
    const int bq = bh >> 3, h = bh & 7;
    const float base = mask[bq * L_ + j] ? -1e9f : 0.f;
    const float bias = relb[(t ? 32 * H_ : 0) + h] * LOG2E;
    (t ? mhi : mlo)[idx] = base + bias;
  }
}

// ---------------- LDS-tiled weight transposes (coalesced both sides) ----------------
__launch_bounds__(256)
__global__ void prep_t(const float* __restrict__ Wqkv, const float* __restrict__ Wo,
                       const float* __restrict__ W1, const float* __restrict__ W2,
                       unsigned short* __restrict__ wqkvt, unsigned short* __restrict__ wot,
                       unsigned short* __restrict__ w1t, unsigned short* __restrict__ w2t) {
  __shared__ float tile[32][33];
  const int bid = blockIdx.x;
  const float* src; unsigned short* dst; int R, C, tr, tc;
  if (bid < 192)      { src = Wqkv; dst = wqkvt; R = 256;  C = 768;  tr = bid / 24;          tc = bid % 24; }
  else if (bid < 256) { src = Wo;   dst = wot;   R = 256;  C = 256;  tr = (bid - 192) >> 3;  tc = (bid - 192) & 7; }
  else if (bid < 512) { src = W1;   dst = w1t;   R = 256;  C = 1024; tr = (bid - 256) >> 5;  tc = (bid - 256) & 31; }
  else                { src = W2;   dst = w2t;   R = 1024; C = 256;  tr = (bid - 512) >> 3;  tc = (bid - 512) & 7; }
  const int tx = threadIdx.x & 31, ty = threadIdx.x >> 5;
#pragma unroll
  for (int i = 0; i < 4; ++i) {
    const int r = tr * 32 + ty + i * 8;
    tile[ty + i * 8][tx] = src[(size_t)r * C + tc * 32 + tx];
  }
  __syncthreads();
#pragma unroll
  for (int i = 0; i < 4; ++i) {
    const int c = tc * 32 + ty + i * 8;
    dst[(size_t)c * R + tr * 32 + tx] = f2bf(tile[tx][ty + i * 8]);
  }
}

// ---------------- GEMM (dbuf, counted vmcnt, XCD-swizzled 1D grid) ----------------
template <int MODE, int TM, int TN, int NBX, int BYG>
__launch_bounds__(256)
__global__ void gemm_k(const unsigned short* __restrict__ A,
                       const unsigned short* __restrict__ Bt,
                       const float* __restrict__ bias,
                       unsigned short* __restrict__ outb0,
                       unsigned short* __restrict__ outb1,
                       unsigned short* __restrict__ outb2,
                       int K)
{
  constexpr int MI = TM / 32, NI = TN / 32;
  __shared__ alignas(16) unsigned short As[2][TM * 64];
  __shared__ alignas(16) unsigned short Bs[2][TN * 64];
  const int tid  = threadIdx.x;
  const int lane = tid & 63, wv = tid >> 6;
  const int wr = wv >> 1, wc = wv & 1;
  const int lr = lane & 15, g = lane >> 4;
  const int bid = blockIdx.x;
  const int xcd = bid & 7, ii = bid >> 3;
  const int by = xcd * BYG + ii / NBX;
  const int bx = ii % NBX;
  const int m0 = by * TM, n0 = bx * TN;
  const int l8 = lane >> 3, jj = lane & 7;

  auto stage = [&](int buf, int k0) {
#pragma unroll
    for (int i = 0; i < MI; ++i) {
      const int row = i * 32 + wv * 8 + l8;
      GLL16(A + (size_t)(m0 + row) * K + k0 + ((jj ^ (row & 7)) * 8),
            &As[buf][i * 2048 + wv * 512]);
    }
#pragma unroll
    for (int i = 0; i < NI; ++i) {
      const int row = i * 32 + wv * 8 + l8;
      GLL16(Bt + (size_t)(n0 + row) * K + k0 + ((jj ^ (row & 7)) * 8),
            &Bs[buf][i * 2048 + wv * 512]);
    }
  };

  f32x4 acc[MI][NI];
#pragma unroll
  for (int i = 0; i < MI; ++i)
#pragma unroll
    for (int j = 0; j < NI; ++j) acc[i][j] = (f32x4)(0.f);

  stage(0, 0);
  for (int k0 = 0; k0 < K; k0 += 64) {
    const int cur = (k0 >> 6) & 1;
    if (k0 + 64 < K) {
      stage(cur ^ 1, k0 + 64);
      asm volatile("s_waitcnt vmcnt(%0)" :: "n"(MI + NI) : "memory");
    } else {
      asm volatile("s_waitcnt vmcnt(0)" ::: "memory");
    }
    __builtin_amdgcn_sched_barrier(0);
    __builtin_amdgcn_s_barrier();
#pragma unroll
    for (int kk = 0; kk < 2; ++kk) {
      FragU af[MI], bf[NI];
#pragma unroll
      for (int mi = 0; mi < MI; ++mi) {
        const int row = wr * (TM / 2) + mi * 16 + lr;
        const int sw = (row & 7) << 3;
        af[mi].q.lo = *(const ull*)&As[cur][row * 64 + ((kk * 32 + 4 * g) ^ sw)];
        af[mi].q.hi = *(const ull*)&As[cur][row * 64 + ((kk * 32 + 16 + 4 * g) ^ sw)];
      }
#pragma unroll
      for (int ni = 0; ni < NI; ++ni) {
        const int row = wc * (TN / 2) + ni * 16 + lr;
        const int sw = (row & 7) << 3;
        bf[ni].q.lo = *(const ull*)&Bs[cur][row * 64 + ((kk * 32 + 4 * g) ^ sw)];
        bf[ni].q.hi = *(const ull*)&Bs[cur][row * 64 + ((kk * 32 + 16 + 4 * g) ^ sw)];
      }
#pragma unroll
      for (int mi = 0; mi < MI; ++mi)
#pragma unroll
        for (int ni = 0; ni < NI; ++ni)
          acc[mi][ni] = __builtin_amdgcn_mfma_f32_16x16x32_bf16(af[mi].v, bf[ni].v, acc[mi][ni], 0, 0, 0);
    }
    asm volatile("s_waitcnt lgkmcnt(0)" ::: "memory");
    __builtin_amdgcn_sched_barrier(0);
    __builtin_amdgcn_s_barrier();
  }

#pragma unroll
  for (int mi = 0; mi < MI; ++mi) {
#pragma unroll
    for (int ni = 0; ni < NI; ++ni) {
      const int n = n0 + wc * (TN / 2) + ni * 16 + lr;
      const float bv = bias[n];
#pragma unroll
      for (int r = 0; r < 4; ++r) {
        const int m = m0 + wr * (TM / 2) + mi * 16 + 4 * g + r;
        float val = acc[mi][ni][r] + bv;
        if constexpr (MODE == 0) {
          const int s = n >> 8, hh = (n >> 5) & 7, dh = n & 31;
          const int bb = m >> 11, l = m & (L_ - 1);
          if (s == 0) {
            outb0[((size_t)(bb * H_ + hh) * L_ + l) * DH_ + dh] =
                f2bf(val * (0.17677669529663687f * LOG2E));
          } else if (s == 1) {
            outb1[((size_t)(bb * H_ + hh) * L_ + l) * DH_ + dh] = f2bf(val);
          } else {
            outb2[((size_t)(bb * H_ + hh) * DH_ + dh) * L_ + l] = f2bf(val);
          }
        } else {
          outb0[(size_t)m * MLP_ + n] = f2bf(fmaxf(val, 0.f));
        }
      }
    }
  }
}

// ---------------- fused GEMM + residual + LayerNorm (LDS-staged, TN=256, TM=16) ----------------
template <bool WRITE_BF>
__launch_bounds__(512)
__global__ void gemmln_k(const unsigned short* __restrict__ A,
                         const unsigned short* __restrict__ Bt,
                         const float* __restrict__ bias,
                         const float* __restrict__ resid,
                         const float* __restrict__ lng,
                         const float* __restrict__ lnb,
                         float* __restrict__ outf,
                         unsigned short* __restrict__ outb,
                         int K)
{
  __shared__ alignas(16) unsigned short As[2][16 * 64];
  __shared__ alignas(16) unsigned short Bs[2][256 * 64];
  __shared__ float rsum[8][16], rsq[8][16], rmu[16], rrstd[16];
  const int tid  = threadIdx.x;
  const int lane = tid & 63, wv = tid >> 6;
  const int lr = lane & 15, g = lane >> 4;
  const int m0 = blockIdx.x * 16;
  const int l8 = lane >> 3, jj = lane & 7;

  auto stage = [&](int buf, int k0) {
    if (wv < 2) {
      const int row = wv * 8 + l8;
      GLL16(A + (size_t)(m0 + row) * K + k0 + ((jj ^ (row & 7)) * 8),
            &As[buf][wv * 512]);
    }
#pragma unroll
    for (int i = 0; i < 4; ++i) {
      const int n = i * 64 + wv * 8 + l8;
      GLL16(Bt + (size_t)n * K + k0 + ((jj ^ (n & 7)) * 8),
            &Bs[buf][i * 4096 + wv * 512]);
    }
  };

  f32x4 acc[2];
  acc[0] = (f32x4)(0.f); acc[1] = (f32x4)(0.f);

  stage(0, 0);
  for (int k0 = 0; k0 < K; k0 += 64) {
    const int cur = (k0 >> 6) & 1;
    if (k0 + 64 < K) {
      stage(cur ^ 1, k0 + 64);
      asm volatile("s_waitcnt vmcnt(4)" ::: "memory");
    } else {
      asm volatile("s_waitcnt vmcnt(0)" ::: "memory");
    }
    __builtin_amdgcn_sched_barrier(0);
    __builtin_amdgcn_s_barrier();
#pragma unroll
    for (int kk = 0; kk < 2; ++kk) {
      FragU af, bf[2];
      {
        const int sw = (lr & 7) << 3;
        af.q.lo = *(const ull*)&As[cur][lr * 64 + ((kk * 32 + 4 * g) ^ sw)];
        af.q.hi = *(const ull*)&As[cur][lr * 64 + ((kk * 32 + 16 + 4 * g) ^ sw)];
      }
#pragma unroll
      for (int ni = 0; ni < 2; ++ni) {
        const int row = wv * 32 + ni * 16 + lr;
        const int sw = (row & 7) << 3;
        bf[ni].q.lo = *(const ull*)&Bs[cur][row * 64 + ((kk * 32 + 4 * g) ^ sw)];
        bf[ni].q.hi = *(const ull*)&Bs[cur][row * 64 + ((kk * 32 + 16 + 4 * g) ^ sw)];
      }
#pragma unroll
      for (int ni = 0; ni < 2; ++ni)
        acc[ni] = __builtin_amdgcn_mfma_f32_16x16x32_bf16(af.v, bf[ni].v, acc[ni], 0, 0, 0);
    }
    asm volatile("s_waitcnt lgkmcnt(0)" ::: "memory");
    __builtin_amdgcn_sched_barrier(0);
    __builtin_amdgcn_s_barrier();
  }

  float g2[2], b2[2], bias2[2];
  int col[2];
#pragma unroll
  for (int ni = 0; ni < 2; ++ni) {
    col[ni] = wv * 32 + ni * 16 + lr;
    g2[ni] = lng[col[ni]]; b2[ni] = lnb[col[ni]]; bias2[ni] = bias[col[ni]];
  }
  float vals[2][4];
#pragma unroll
  for (int r = 0; r < 4; ++r) {
    const int row = 4 * g + r;
    float s = 0.f, q = 0.f;
#pragma unroll
    for (int ni = 0; ni < 2; ++ni) {
      float v = acc[ni][r] + bias2[ni] + resid[(size_t)(m0 + row) * D_ + col[ni]];
      vals[ni][r] = v; s += v; q += v * v;
    }
#pragma unroll
    for (int off = 1; off < 16; off <<= 1) {
      s += __shfl_xor(s, off); q += __shfl_xor(q, off);
    }
    if (lr == 0) { rsum[wv][row] = s; rsq[wv][row] = q; }
  }
  __syncthreads();
  if (tid < 16) {
    float s = 0.f, q = 0.f;
#pragma unroll
    for (int w = 0; w < 8; ++w) { s += rsum[w][tid]; q += rsq[w][tid]; }
    const float mu = s * (1.f / D_);
    rmu[tid] = mu;
    rrstd[tid] = rsqrtf(q * (1.f / D_) - mu * mu + 1e-5f);
  }
  __syncthreads();
#pragma unroll
  for (int r = 0; r < 4; ++r) {
    const int row = 4 * g + r;
    const float mu = rmu[row], rs = rrstd[row];
#pragma unroll
    for (int ni = 0; ni < 2; ++ni) {
      const float o = (vals[ni][r] - mu) * rs * g2[ni] + b2[ni];
      const size_t idx = (size_t)(m0 + row) * D_ + col[ni];
      outf[idx] = o;
      if constexpr (WRITE_BF) outb[idx] = f2bf(o);
    }
  }
}

// ---------------- flash attention (R13 structure restored): 128 q/block
// (8 waves x 16 q), KV chunk 128, Ks LDS write-late dbuf + V gll16 dbuf,
// one barrier per chunk, max-free softmax, pre-biased far-field tables,
// XCD-swizzled 1D grid. ----------------
__launch_bounds__(512)
__global__ void attn_k(const unsigned short* __restrict__ qb,
                       const unsigned short* __restrict__ kp,
                       const unsigned short* __restrict__ vT,
                       const float* __restrict__ maskf,
                       const float* __restrict__ mlo,
                       const float* __restrict__ mhi,
                       const float* __restrict__ relb,
                       unsigned short* __restrict__ aout)
{
  __shared__ alignas(16) unsigned short Ks[2][128 * 40];   // padded rows (80B)
  __shared__ alignas(16) unsigned short Vs[2][32 * 128];   // XOR-swizzled
  __shared__ alignas(16) float biasv[36];
  const int tid = threadIdx.x;
  const int lane = tid & 63, wv = tid >> 6;                // wv in 0..7
  const int lr = lane & 15, g = lane >> 4;
  // XCD-aware decode: 512 blocks = 8 xcd * 4 bh * 16 qblk (bijective)
  const int bid = blockIdx.x;
  const int ii = bid >> 3;
  const int bh = (bid & 7) * 4 + (ii >> 4);
  const int qblk = ii & 15;
  const int b = bh >> 3, h = bh & 7;
  const size_t bhoff = (size_t)bh * (L_ * DH_);
  if (tid < 33) biasv[tid] = relb[tid * H_ + h] * LOG2E;
  const int qw0 = qblk * 128 + wv * 16;

  FragU qf;
  {
    const unsigned short* qr = qb + bhoff + (size_t)(qw0 + lr) * DH_;
    qf.q.lo = *(const ull*)(qr + 4 * g);
    qf.q.hi = *(const ull*)(qr + 16 + 4 * g);
  }
  f32x4 O0 = (f32x4)(0.f), O1 = (f32x4)(0.f);
  f32x2 ssum2 = {0.f, 0.f};
  const f32x4 z4 = (f32x4)(0.f);
  const int krow = tid >> 2, koff = (tid & 3) * 8;         // 512 thr: 16B/thread
  const float* mtl = mlo + (size_t)bh * L_ + 4 * g;
  const float* mth = mhi + (size_t)bh * L_ + 4 * g;
  const float* mbn = maskf + (size_t)b * L_ + 4 * g;

  // prologue: stage chunk 0 into buffers[0]
  {
    const int4 ka = *(const int4*)(kp + bhoff + (size_t)krow * DH_ + koff);
    const int d = wv * 4 + (lane >> 4);
    GLL16(vT + ((size_t)bh * DH_ + d) * L_ + (((lane & 15) * 8) ^ ((d & 7) * 8)),
          &Vs[0][wv * 512]);
    *(int4*)&Ks[0][krow * 40 + koff] = ka;
    asm volatile("s_waitcnt vmcnt(0) lgkmcnt(0)" ::: "memory");
    __builtin_amdgcn_s_barrier();
  }

#pragma unroll 2
  for (int ch = 0; ch < 16; ++ch) {
    const int cur = ch & 1, nxt = cur ^ 1;
    const int kv = ch * 128;
    const bool more = ch < 15;
    int4 ka = {0, 0, 0, 0};
    if (more) {   // prefetch chunk ch+1: K->regs, V->LDS[nxt] via gll16
      ka = *(const int4*)(kp + bhoff + (size_t)(kv + 128 + krow) * DH_ + koff);
      const int d = wv * 4 + (lane >> 4);
      GLL16(vT + ((size_t)bh * DH_ + d) * L_ + kv + 128 + (((lane & 15) * 8) ^ ((d & 7) * 8)),
            &Vs[nxt][wv * 512]);
    }

    // hoisted QK phase: both sub-tiles' K frags + 8 MFMAs up front
    SU sT[2][4];
#pragma unroll
    for (int st = 0; st < 2; ++st) {
      const unsigned short* KsC = &Ks[cur][st * 64 * 40];
#pragma unroll
      for (int jt = 0; jt < 4; ++jt) {
        FragU kf;
        const int base = (jt * 16 + lr) * 40;
        kf.q.lo = *(const ull*)&KsC[base + 4 * g];
        kf.q.hi = *(const ull*)&KsC[base + 16 + 4 * g];
        sT[st][jt].v4 = __builtin_amdgcn_mfma_f32_16x16x32_bf16(kf.v, qf.v, z4, 0, 0, 0);
      }
    }

#pragma unroll
    for (int st = 0; st < 2; ++st) {
      const int j0 = kv + st * 64;
      const int dlt = j0 - qw0;
      if (dlt >= 32 || dlt <= -80) {          // far field: pre-biased table
        const float* mt = (dlt > 0) ? mth : mtl;
#pragma unroll
        for (int jt = 0; jt < 4; ++jt) {
          SU mk; mk.v4 = *(const f32x4*)(mt + j0 + jt * 16);
          sT[st][jt].v2[0] = pk_add(sT[st][jt].v2[0], mk.v2[0]);
          sT[st][jt].v2[1] = pk_add(sT[st][jt].v2[1], mk.v2[1]);
        }
      } else {                                 // near field (2 of 32 sub-tiles)
#pragma unroll
        for (int jt = 0; jt < 4; ++jt)
#pragma unroll
          for (int r = 0; r < 4; ++r) {
            int rel = j0 + jt * 16 + 4 * g + r - (qw0 + lr);
            rel = rel < -16 ? -16 : (rel > 16 ? 16 : rel);
            sT[st][jt].v4[r] += biasv[rel + 16] + mbn[j0 + jt * 16 + r];
          }
      }
      // max-free: p = exp2(s) directly (masked -> 0)
#pragma unroll
      for (int jt = 0; jt < 4; ++jt)
#pragma unroll
        for (int r = 0; r < 4; ++r)
          sT[st][jt].v4[r] = fexp2(sT[st][jt].v4[r]);
      // packed partial-sum accumulate
      const f32x2 s01 = pk_add(sT[st][0].v2[0], sT[st][0].v2[1]);
      const f32x2 s23 = pk_add(sT[st][1].v2[0], sT[st][1].v2[1]);
      const f32x2 s45 = pk_add(sT[st][2].v2[0], sT[st][2].v2[1]);
      const f32x2 s67 = pk_add(sT[st][3].v2[0], sT[st][3].v2[1]);
      ssum2 = pk_add(ssum2, pk_add(pk_add(s01, s23), pk_add(s45, s67)));

      FragU a0, a1;
      a0.u[0] = cvt_pk_bf16(sT[st][0].v4[0], sT[st][0].v4[1]);
      a0.u[1] = cvt_pk_bf16(sT[st][0].v4[2], sT[st][0].v4[3]);
      a0.u[2] = cvt_pk_bf16(sT[st][1].v4[0], sT[st][1].v4[1]);
      a0.u[3] = cvt_pk_bf16(sT[st][1].v4[2], sT[st][1].v4[3]);
      a1.u[0] = cvt_pk_bf16(sT[st][2].v4[0], sT[st][2].v4[1]);
      a1.u[1] = cvt_pk_bf16(sT[st][2].v4[2], sT[st][2].v4[3]);
      a1.u[2] = cvt_pk_bf16(sT[st][3].v4[0], sT[st][3].v4[1]);
      a1.u[3] = cvt_pk_bf16(sT[st][3].v4[2], sT[st][3].v4[3]);

      FragU vf00, vf01, vf10, vf11;
#pragma unroll
      for (int dt = 0; dt < 2; ++dt) {
        const int row = dt * 16 + lr;
        const int sw = (row & 7) << 3;
        FragU v0, v1;
        v0.q.lo = *(const ull*)&Vs[cur][row * 128 + ((st * 64 + 4 * g) ^ sw)];
        v0.q.hi = *(const ull*)&Vs[cur][row * 128 + ((st * 64 + 16 + 4 * g) ^ sw)];
        v1.q.lo = *(const ull*)&Vs[cur][row * 128 + ((st * 64 + 32 + 4 * g) ^ sw)];
        v1.q.hi = *(const ull*)&Vs[cur][row * 128 + ((st * 64 + 48 + 4 * g) ^ sw)];
        if (dt == 0) { vf00 = v0; vf01 = v1; } else { vf10 = v0; vf11 = v1; }
      }
      O0 = __builtin_amdgcn_mfma_f32_16x16x32_bf16(a0.v, vf00.v, O0, 0, 0, 0);
      O0 = __builtin_amdgcn_mfma_f32_16x16x32_bf16(a1.v, vf01.v, O0, 0, 0, 0);
      O1 = __builtin_amdgcn_mfma_f32_16x16x32_bf16(a0.v, vf10.v, O1, 0, 0, 0);
      O1 = __builtin_amdgcn_mfma_f32_16x16x32_bf16(a1.v, vf11.v, O1, 0, 0, 0);
    }

    if (more) {  // write-late K into next buffer
      *(int4*)&Ks[nxt][krow * 40 + koff] = ka;
    }
    asm volatile("s_waitcnt vmcnt(0) lgkmcnt(0)" ::: "memory");
    __builtin_amdgcn_sched_barrier(0);
    __builtin_amdgcn_s_barrier();
  }

  // epilogue: reduce denominator, write O
  float ssum = ssum2[0] + ssum2[1];
  ssum += __shfl_xor(ssum, 16);
  ssum += __shfl_xor(ssum, 32);
#pragma unroll
  for (int r = 0; r < 4; ++r) {
    const float sden = __shfl(ssum, 4 * g + r);
    const float inv = 1.f / sden;
    const int qo = qw0 + 4 * g + r;
    unsigned short* orow = aout + ((size_t)(b * L_ + qo)) * D_ + h * DH_;
    orow[lr]      = f2bf(O0[r] * inv);
    orow[16 + lr] = f2bf(O1[r] * inv);
  }
}

// ---------------- launch ----------------
extern "C" void kernel_launch(void* const* d_in, const int* in_sizes, int n_in,
                              void* d_out, int out_size, void* d_ws, size_t ws_size,
                              hipStream_t stream) {
  (void)in_sizes; (void)n_in; (void)out_size; (void)ws_size;
  const float* x    = (const float*)d_in[0];
  const int*   mask = (const int*)d_in[1];
  const float* Wqkv = (const float*)d_in[2];
  const float* bqkv = (const float*)d_in[3];
  const float* Wo   = (const float*)d_in[4];
  const float* bo   = (const float*)d_in[5];
  const float* ln1g = (const float*)d_in[6];
  const float* ln1b = (const float*)d_in[7];
  const float* W1   = (const float*)d_in[8];
  const float* b1   = (const float*)d_in[9];
  const float* W2   = (const float*)d_in[10];
  const float* b2   = (const float*)d_in[11];
  const float* ln2g = (const float*)d_in[12];
  const float* ln2b = (const float*)d_in[13];
  const float* relb = (const float*)d_in[14];

  size_t off = 0;
  char* wsb = (char*)d_ws;
  auto carve = [&](size_t bytes) -> void* {
    void* p = wsb + off;
    off += (bytes + 255) & ~(size_t)255;
    return p;
  };
  const size_t tokb = (size_t)B_ * L_;
  unsigned short* xb    = (unsigned short*)carve(tokb * D_ * 2);
  unsigned short* qbuf  = (unsigned short*)carve(tokb * D_ * 2);
  unsigned short* kbuf  = (unsigned short*)carve(tokb * D_ * 2);
  unsigned short* vTb   = (unsigned short*)carve(tokb * D_ * 2);
  unsigned short* attnb = (unsigned short*)carve(tokb * D_ * 2);
  unsigned short* wqkvt = (unsigned short*)carve((size_t)3 * D_ * D_ * 2);
  unsigned short* wot   = (unsigned short*)carve((size_t)D_ * D_ * 2);
  unsigned short* w1t   = (unsigned short*)carve((size_t)D_ * MLP_ * 2);
  unsigned short* w2t   = (unsigned short*)carve((size_t)D_ * MLP_ * 2);
  float*          x1    = (float*)carve(tokb * D_ * 4);
  unsigned short* x1b   = (unsigned short*)carve(tokb * D_ * 2);
  unsigned short* hbuf  = (unsigned short*)carve(tokb * MLP_ * 2);
  float*          maskfb = (float*)carve(tokb * 4);
  float*          mlob  = (float*)carve((size_t)B_ * H_ * L_ * 4);
  float*          mhib  = (float*)carve((size_t)B_ * H_ * L_ * 4);

  prep_w<<<2592, 256, 0, stream>>>(x, mask, relb, xb, maskfb, mlob, mhib);
  prep_t<<<768, 256, 0, stream>>>(Wqkv, Wo, W1, W2, wqkvt, wot, w1t, w2t);

  // qkv: nbx=6, nby=128 -> 768 blocks = 6*8*16
  gemm_k<0, 64, 128, 6, 16><<<768, 256, 0, stream>>>(
      xb, wqkvt, bqkv, qbuf, kbuf, vTb, D_);
  // attn: 512 blocks = 8 xcd * 4 bh * 16 qblk, 128 q/block
  attn_k<<<512, 512, 0, stream>>>(
      qbuf, kbuf, vTb, maskfb, mlob, mhib, relb, attnb);
  gemmln_k<true><<<tokb / 16, 512, 0, stream>>>(
      attnb, wot, bo, x, ln1g, ln1b, x1, x1b, D_);
  // mlp1: nbx=8, nby=128 -> 1024 blocks = 8*8*16
  gemm_k<2, 64, 128, 8, 16><<<1024, 256, 0, stream>>>(
      x1b, w1t, b1, hbuf, nullptr, nullptr, D_);
  gemmln_k<false><<<tokb / 16, 512, 0, stream>>>(
      hbuf, w2t, b2, x1, ln2g, ln2b, (float*)d_out, nullptr, MLP_);
}

// Round 16
// 104.405 us; speedup vs baseline: 1.2111x; 1.0607x over previous
//
#include <hip/hip_runtime.h>

#define B_   4
#define L_   2048
#define D_   256
#define H_   8
#define DH_  32
#define MLP_ 1024
#define LOG2E 1.4426950408889634f

typedef __attribute__((ext_vector_type(8))) short  short8;
typedef __attribute__((ext_vector_type(4))) float  f32x4;
typedef __attribute__((ext_vector_type(2))) float  f32x2;
typedef unsigned long long ull;

union FragU { short8 v; struct { ull lo, hi; } q; unsigned u[4]; };
union SU { f32x4 v4; f32x2 v2[2]; };

__device__ __forceinline__ unsigned short f2bf(float f) {
  unsigned u = __float_as_uint(f);
  u += 0x7fffu + ((u >> 16) & 1u);
  return (unsigned short)(u >> 16);
}

__device__ __forceinline__ ull pack4(float a, float b, float c, float d) {
  return (ull)f2bf(a) | ((ull)f2bf(b) << 16) | ((ull)f2bf(c) << 32) | ((ull)f2bf(d) << 48);
}

__device__ __forceinline__ unsigned cvt_pk_bf16(float lo, float hi) {
  unsigned r;
  asm("v_cvt_pk_bf16_f32 %0, %1, %2" : "=v"(r) : "v"(lo), "v"(hi));
  return r;
}

// packed f32 add (legal VOP3P on gfx950; pk_max is NOT)
__device__ __forceinline__ f32x2 pk_add(f32x2 a, f32x2 b) {
  f32x2 r; asm("v_pk_add_f32 %0, %1, %2" : "=v"(r) : "v"(a), "v"(b)); return r;
}

__device__ __forceinline__ float fexp2(float x) {
#if __has_builtin(__builtin_amdgcn_exp2f)
  return __builtin_amdgcn_exp2f(x);
#else
  return exp2f(x);
#endif
}

#define GLL16(gp, lp) __builtin_amdgcn_global_load_lds( \
    (const __attribute__((address_space(1))) void*)(gp), \
    (__attribute__((address_space(3))) void*)(lp), 16, 0, 0)

// ---------------- all input prep, ONE launch ----------------
// blocks 0..767: LDS-tiled weight transposes (coalesced both sides)
// blocks 768.. : x->bf16, mask->float, pre-biased far-field tables
__launch_bounds__(256)
__global__ void prep_all(const float* __restrict__ x,
                         const int* __restrict__ mask, const float* __restrict__ relb,
                         const float* __restrict__ Wqkv, const float* __restrict__ Wo,
                         const float* __restrict__ W1, const float* __restrict__ W2,
                         unsigned short* __restrict__ xb,
                         float* __restrict__ maskf,
                         float* __restrict__ mlo, float* __restrict__ mhi,
                         unsigned short* __restrict__ wqkvt, unsigned short* __restrict__ wot,
                         unsigned short* __restrict__ w1t, unsigned short* __restrict__ w2t) {
  __shared__ float tile[32][33];
  const int bid = blockIdx.x;
  if (bid < 768) {
    const float* src; unsigned short* dst; int R, C, tr, tc;
    if (bid < 192)      { src = Wqkv; dst = wqkvt; R = 256;  C = 768;  tr = bid / 24;          tc = bid % 24; }
    else if (bid < 256) { src = Wo;   dst = wot;   R = 256;  C = 256;  tr = (bid - 192) >> 3;  tc = (bid - 192) & 7; }
    else if (bid < 512) { src = W1;   dst = w1t;   R = 256;  C = 1024; tr = (bid - 256) >> 5;  tc = (bid - 256) & 31; }
    else                { src = W2;   dst = w2t;   R = 1024; C = 256;  tr = (bid - 512) >> 3;  tc = (bid - 512) & 7; }
    const int tx = threadIdx.x & 31, ty = threadIdx.x >> 5;
#pragma unroll
    for (int i = 0; i < 4; ++i) {
      const int r = tr * 32 + ty + i * 8;
      tile[ty + i * 8][tx] = src[(size_t)r * C + tc * 32 + tx];
    }
    __syncthreads();
#pragma unroll
    for (int i = 0; i < 4; ++i) {
      const int c = tc * 32 + ty + i * 8;
      dst[(size_t)c * R + tr * 32 + tx] = f2bf(tile[tx][ty + i * 8]);
    }
  } else {
    const int i = (bid - 768) * 256 + threadIdx.x;
    if (i < 524288) {            // x: 2,097,152 floats, 4 per thread
      const float4 v = *(const float4*)(x + (size_t)i * 4);
      *(ull*)(xb + (size_t)i * 4) = pack4(v.x, v.y, v.z, v.w);
    } else if (i < 532480) {     // raw mask -> additive float [B,L]
      const int j = i - 524288;
      maskf[j] = mask[j] ? -1e9f : 0.f;
    } else {                     // pre-biased far-field tables [B*H][L], lo and hi
      const int j2 = i - 532480;
      const int t = j2 >> 16, idx = j2 & 65535;
      const int bh = idx >> 11, j = idx & 2047;
      const int bq = bh >> 3, h = bh & 7;
      const float base = mask[bq * L_ + j] ? -1e9f : 0.f;
      const float bias = relb[(t ? 32 * H_ : 0) + h] * LOG2E;
      (t ? mhi : mlo)[idx] = base + bias;
    }
  }
}

// ---------------- GEMM (dbuf, counted vmcnt, XCD-swizzled 1D grid) ----------------
template <int MODE, int TM, int TN, int NBX, int BYG>
__launch_bounds__(256)
__global__ void gemm_k(const unsigned short* __restrict__ A,
                       const unsigned short* __restrict__ Bt,
                       const float* __restrict__ bias,
                       unsigned short* __restrict__ outb0,
                       unsigned short* __restrict__ outb1,
                       unsigned short* __restrict__ outb2,
                       int K)
{
  constexpr int MI = TM / 32, NI = TN / 32;
  __shared__ alignas(16) unsigned short As[2][TM * 64];
  __shared__ alignas(16) unsigned short Bs[2][TN * 64];
  const int tid  = threadIdx.x;
  const int lane = tid & 63, wv = tid >> 6;
  const int wr = wv >> 1, wc = wv & 1;
  const int lr = lane & 15, g = lane >> 4;
  const int bid = blockIdx.x;
  const int xcd = bid & 7, ii = bid >> 3;
  const int by = xcd * BYG + ii / NBX;
  const int bx = ii % NBX;
  const int m0 = by * TM, n0 = bx * TN;
  const int l8 = lane >> 3, jj = lane & 7;

  auto stage = [&](int buf, int k0) {
#pragma unroll
    for (int i = 0; i < MI; ++i) {
      const int row = i * 32 + wv * 8 + l8;
      GLL16(A + (size_t)(m0 + row) * K + k0 + ((jj ^ (row & 7)) * 8),
            &As[buf][i * 2048 + wv * 512]);
    }
#pragma unroll
    for (int i = 0; i < NI; ++i) {
      const int row = i * 32 + wv * 8 + l8;
      GLL16(Bt + (size_t)(n0 + row) * K + k0 + ((jj ^ (row & 7)) * 8),
            &Bs[buf][i * 2048 + wv * 512]);
    }
  };

  f32x4 acc[MI][NI];
#pragma unroll
  for (int i = 0; i < MI; ++i)
#pragma unroll
    for (int j = 0; j < NI; ++j) acc[i][j] = (f32x4)(0.f);

  stage(0, 0);
  for (int k0 = 0; k0 < K; k0 += 64) {
    const int cur = (k0 >> 6) & 1;
    if (k0 + 64 < K) {
      stage(cur ^ 1, k0 + 64);
      asm volatile("s_waitcnt vmcnt(%0)" :: "n"(MI + NI) : "memory");
    } else {
      asm volatile("s_waitcnt vmcnt(0)" ::: "memory");
    }
    __builtin_amdgcn_sched_barrier(0);
    __builtin_amdgcn_s_barrier();
#pragma unroll
    for (int kk = 0; kk < 2; ++kk) {
      FragU af[MI], bf[NI];
#pragma unroll
      for (int mi = 0; mi < MI; ++mi) {
        const int row = wr * (TM / 2) + mi * 16 + lr;
        const int sw = (row & 7) << 3;
        af[mi].q.lo = *(const ull*)&As[cur][row * 64 + ((kk * 32 + 4 * g) ^ sw)];
        af[mi].q.hi = *(const ull*)&As[cur][row * 64 + ((kk * 32 + 16 + 4 * g) ^ sw)];
      }
#pragma unroll
      for (int ni = 0; ni < NI; ++ni) {
        const int row = wc * (TN / 2) + ni * 16 + lr;
        const int sw = (row & 7) << 3;
        bf[ni].q.lo = *(const ull*)&Bs[cur][row * 64 + ((kk * 32 + 4 * g) ^ sw)];
        bf[ni].q.hi = *(const ull*)&Bs[cur][row * 64 + ((kk * 32 + 16 + 4 * g) ^ sw)];
      }
#pragma unroll
      for (int mi = 0; mi < MI; ++mi)
#pragma unroll
        for (int ni = 0; ni < NI; ++ni)
          acc[mi][ni] = __builtin_amdgcn_mfma_f32_16x16x32_bf16(af[mi].v, bf[ni].v, acc[mi][ni], 0, 0, 0);
    }
    asm volatile("s_waitcnt lgkmcnt(0)" ::: "memory");
    __builtin_amdgcn_sched_barrier(0);
    __builtin_amdgcn_s_barrier();
  }

#pragma unroll
  for (int mi = 0; mi < MI; ++mi) {
#pragma unroll
    for (int ni = 0; ni < NI; ++ni) {
      const int n = n0 + wc * (TN / 2) + ni * 16 + lr;
      const float bv = bias[n];
#pragma unroll
      for (int r = 0; r < 4; ++r) {
        const int m = m0 + wr * (TM / 2) + mi * 16 + 4 * g + r;
        float val = acc[mi][ni][r] + bv;
        if constexpr (MODE == 0) {
          const int s = n >> 8, hh = (n >> 5) & 7, dh = n & 31;
          const int bb = m >> 11, l = m & (L_ - 1);
          if (s == 0) {
            outb0[((size_t)(bb * H_ + hh) * L_ + l) * DH_ + dh] =
                f2bf(val * (0.17677669529663687f * LOG2E));
          } else if (s == 1) {
            outb1[((size_t)(bb * H_ + hh) * L_ + l) * DH_ + dh] = f2bf(val);
          } else {
            outb2[((size_t)(bb * H_ + hh) * DH_ + dh) * L_ + l] = f2bf(val);
          }
        } else {
          outb0[(size_t)m * MLP_ + n] = f2bf(fmaxf(val, 0.f));
        }
      }
    }
  }
}

// ---------------- fused GEMM + residual + LayerNorm (LDS-staged, TN=256, TM=16) ----------------
template <bool WRITE_BF>
__launch_bounds__(512)
__global__ void gemmln_k(const unsigned short* __restrict__ A,
                         const unsigned short* __restrict__ Bt,
                         const float* __restrict__ bias,
                         const float* __restrict__ resid,
                         const float* __restrict__ lng,
                         const float* __restrict__ lnb,
                         float* __restrict__ outf,
                         unsigned short* __restrict__ outb,
                         int K)
{
  __shared__ alignas(16) unsigned short As[2][16 * 64];
  __shared__ alignas(16) unsigned short Bs[2][256 * 64];
  __shared__ float rsum[8][16], rsq[8][16], rmu[16], rrstd[16];
  const int tid  = threadIdx.x;
  const int lane = tid & 63, wv = tid >> 6;
  const int lr = lane & 15, g = lane >> 4;
  const int m0 = blockIdx.x * 16;
  const int l8 = lane >> 3, jj = lane & 7;

  auto stage = [&](int buf, int k0) {
    if (wv < 2) {
      const int row = wv * 8 + l8;
      GLL16(A + (size_t)(m0 + row) * K + k0 + ((jj ^ (row & 7)) * 8),
            &As[buf][wv * 512]);
    }
#pragma unroll
    for (int i = 0; i < 4; ++i) {
      const int n = i * 64 + wv * 8 + l8;
      GLL16(Bt + (size_t)n * K + k0 + ((jj ^ (n & 7)) * 8),
            &Bs[buf][i * 4096 + wv * 512]);
    }
  };

  f32x4 acc[2];
  acc[0] = (f32x4)(0.f); acc[1] = (f32x4)(0.f);

  stage(0, 0);
  for (int k0 = 0; k0 < K; k0 += 64) {
    const int cur = (k0 >> 6) & 1;
    if (k0 + 64 < K) {
      stage(cur ^ 1, k0 + 64);
      asm volatile("s_waitcnt vmcnt(4)" ::: "memory");
    } else {
      asm volatile("s_waitcnt vmcnt(0)" ::: "memory");
    }
    __builtin_amdgcn_sched_barrier(0);
    __builtin_amdgcn_s_barrier();
#pragma unroll
    for (int kk = 0; kk < 2; ++kk) {
      FragU af, bf[2];
      {
        const int sw = (lr & 7) << 3;
        af.q.lo = *(const ull*)&As[cur][lr * 64 + ((kk * 32 + 4 * g) ^ sw)];
        af.q.hi = *(const ull*)&As[cur][lr * 64 + ((kk * 32 + 16 + 4 * g) ^ sw)];
      }
#pragma unroll
      for (int ni = 0; ni < 2; ++ni) {
        const int row = wv * 32 + ni * 16 + lr;
        const int sw = (row & 7) << 3;
        bf[ni].q.lo = *(const ull*)&Bs[cur][row * 64 + ((kk * 32 + 4 * g) ^ sw)];
        bf[ni].q.hi = *(const ull*)&Bs[cur][row * 64 + ((kk * 32 + 16 + 4 * g) ^ sw)];
      }
#pragma unroll
      for (int ni = 0; ni < 2; ++ni)
        acc[ni] = __builtin_amdgcn_mfma_f32_16x16x32_bf16(af.v, bf[ni].v, acc[ni], 0, 0, 0);
    }
    asm volatile("s_waitcnt lgkmcnt(0)" ::: "memory");
    __builtin_amdgcn_sched_barrier(0);
    __builtin_amdgcn_s_barrier();
  }

  float g2[2], b2[2], bias2[2];
  int col[2];
#pragma unroll
  for (int ni = 0; ni < 2; ++ni) {
    col[ni] = wv * 32 + ni * 16 + lr;
    g2[ni] = lng[col[ni]]; b2[ni] = lnb[col[ni]]; bias2[ni] = bias[col[ni]];
  }
  float vals[2][4];
#pragma unroll
  for (int r = 0; r < 4; ++r) {
    const int row = 4 * g + r;
    float s = 0.f, q = 0.f;
#pragma unroll
    for (int ni = 0; ni < 2; ++ni) {
      float v = acc[ni][r] + bias2[ni] + resid[(size_t)(m0 + row) * D_ + col[ni]];
      vals[ni][r] = v; s += v; q += v * v;
    }
#pragma unroll
    for (int off = 1; off < 16; off <<= 1) {
      s += __shfl_xor(s, off); q += __shfl_xor(q, off);
    }
    if (lr == 0) { rsum[wv][row] = s; rsq[wv][row] = q; }
  }
  __syncthreads();
  if (tid < 16) {
    float s = 0.f, q = 0.f;
#pragma unroll
    for (int w = 0; w < 8; ++w) { s += rsum[w][tid]; q += rsq[w][tid]; }
    const float mu = s * (1.f / D_);
    rmu[tid] = mu;
    rrstd[tid] = rsqrtf(q * (1.f / D_) - mu * mu + 1e-5f);
  }
  __syncthreads();
#pragma unroll
  for (int r = 0; r < 4; ++r) {
    const int row = 4 * g + r;
    const float mu = rmu[row], rs = rrstd[row];
#pragma unroll
    for (int ni = 0; ni < 2; ++ni) {
      const float o = (vals[ni][r] - mu) * rs * g2[ni] + b2[ni];
      const size_t idx = (size_t)(m0 + row) * D_ + col[ni];
      outf[idx] = o;
      if constexpr (WRITE_BF) outb[idx] = f2bf(o);
    }
  }
}

// ---------------- flash attention: 128 q/block (8 waves x 16 q), KV chunk 128,
// Ks LDS write-late dbuf + V gll16 dbuf, one barrier per chunk, max-free
// softmax, pre-biased far-field tables, XCD-swizzled 1D grid.
// QK frags use sigma(g,i)=8g+i on BOTH operands: Q = one short8 global load,
// K = one ds_read_b128 per frag (16B-aligned: row stride 80B, offset 16g B). ----------------
__launch_bounds__(512)
__global__ void attn_k(const unsigned short* __restrict__ qb,
                       const unsigned short* __restrict__ kp,
                       const unsigned short* __restrict__ vT,
                       const float* __restrict__ maskf,
                       const float* __restrict__ mlo,
                       const float* __restrict__ mhi,
                       const float* __restrict__ relb,
                       unsigned short* __restrict__ aout)
{
  __shared__ alignas(16) unsigned short Ks[2][128 * 40];   // padded rows (80B)
  __shared__ alignas(16) unsigned short Vs[2][32 * 128];   // XOR-swizzled
  __shared__ alignas(16) float biasv[36];
  const int tid = threadIdx.x;
  const int lane = tid & 63, wv = tid >> 6;                // wv in 0..7
  const int lr = lane & 15, g = lane >> 4;
  // XCD-aware decode: 512 blocks = 8 xcd * 4 bh * 16 qblk (bijective)
  const int bid = blockIdx.x;
  const int ii = bid >> 3;
  const int bh = (bid & 7) * 4 + (ii >> 4);
  const int qblk = ii & 15;
  const int b = bh >> 3, h = bh & 7;
  const size_t bhoff = (size_t)bh * (L_ * DH_);
  if (tid < 33) biasv[tid] = relb[tid * H_ + h] * LOG2E;
  const int qw0 = qblk * 128 + wv * 16;

  FragU qf;
  qf.v = *(const short8*)(qb + bhoff + (size_t)(qw0 + lr) * DH_ + 8 * g);

  f32x4 O0 = (f32x4)(0.f), O1 = (f32x4)(0.f);
  f32x2 ssum2 = {0.f, 0.f};
  const f32x4 z4 = (f32x4)(0.f);
  const int krow = tid >> 2, koff = (tid & 3) * 8;         // 512 thr: 16B/thread
  const float* mtl = mlo + (size_t)bh * L_ + 4 * g;
  const float* mth = mhi + (size_t)bh * L_ + 4 * g;
  const float* mbn = maskf + (size_t)b * L_ + 4 * g;

  // prologue: stage chunk 0 into buffers[0]
  {
    const int4 ka = *(const int4*)(kp + bhoff + (size_t)krow * DH_ + koff);
    const int d = wv * 4 + (lane >> 4);
    GLL16(vT + ((size_t)bh * DH_ + d) * L_ + (((lane & 15) * 8) ^ ((d & 7) * 8)),
          &Vs[0][wv * 512]);
    *(int4*)&Ks[0][krow * 40 + koff] = ka;
    asm volatile("s_waitcnt vmcnt(0) lgkmcnt(0)" ::: "memory");
    __builtin_amdgcn_s_barrier();
  }

#pragma unroll 2
  for (int ch = 0; ch < 16; ++ch) {
    const int cur = ch & 1, nxt = cur ^ 1;
    const int kv = ch * 128;
    const bool more = ch < 15;
    int4 ka = {0, 0, 0, 0};
    if (more) {   // prefetch chunk ch+1: K->regs, V->LDS[nxt] via gll16
      ka = *(const int4*)(kp + bhoff + (size_t)(kv + 128 + krow) * DH_ + koff);
      const int d = wv * 4 + (lane >> 4);
      GLL16(vT + ((size_t)bh * DH_ + d) * L_ + kv + 128 + (((lane & 15) * 8) ^ ((d & 7) * 8)),
            &Vs[nxt][wv * 512]);
    }

    // hoisted QK phase: both sub-tiles' K frags (one b128 each) + 8 MFMAs
    SU sT[2][4];
#pragma unroll
    for (int st = 0; st < 2; ++st) {
      const unsigned short* KsC = &Ks[cur][st * 64 * 40];
#pragma unroll
      for (int jt = 0; jt < 4; ++jt) {
        FragU kf;
        kf.v = *(const short8*)&KsC[(jt * 16 + lr) * 40 + 8 * g];
        sT[st][jt].v4 = __builtin_amdgcn_mfma_f32_16x16x32_bf16(kf.v, qf.v, z4, 0, 0, 0);
      }
    }

#pragma unroll
    for (int st = 0; st < 2; ++st) {
      const int j0 = kv + st * 64;
      const int dlt = j0 - qw0;
      if (dlt >= 32 || dlt <= -80) {          // far field: pre-biased table
        const float* mt = (dlt > 0) ? mth : mtl;
#pragma unroll
        for (int jt = 0; jt < 4; ++jt) {
          SU mk; mk.v4 = *(const f32x4*)(mt + j0 + jt * 16);
          sT[st][jt].v2[0] = pk_add(sT[st][jt].v2[0], mk.v2[0]);
          sT[st][jt].v2[1] = pk_add(sT[st][jt].v2[1], mk.v2[1]);
        }
      } else {                                 // near field (2 of 32 sub-tiles)
#pragma unroll
        for (int jt = 0; jt < 4; ++jt)
#pragma unroll
          for (int r = 0; r < 4; ++r) {
            int rel = j0 + jt * 16 + 4 * g + r - (qw0 + lr);
            rel = rel < -16 ? -16 : (rel > 16 ? 16 : rel);
            sT[st][jt].v4[r] += biasv[rel + 16] + mbn[j0 + jt * 16 + r];
          }
      }
      // max-free: p = exp2(s) directly (masked -> 0)
#pragma unroll
      for (int jt = 0; jt < 4; ++jt)
#pragma unroll
        for (int r = 0; r < 4; ++r)
          sT[st][jt].v4[r] = fexp2(sT[st][jt].v4[r]);
      // packed partial-sum accumulate
      const f32x2 s01 = pk_add(sT[st][0].v2[0], sT[st][0].v2[1]);
      const f32x2 s23 = pk_add(sT[st][1].v2[0], sT[st][1].v2[1]);
      const f32x2 s45 = pk_add(sT[st][2].v2[0], sT[st][2].v2[1]);
      const f32x2 s67 = pk_add(sT[st][3].v2[0], sT[st][3].v2[1]);
      ssum2 = pk_add(ssum2, pk_add(pk_add(s01, s23), pk_add(s45, s67)));

      FragU a0, a1;
      a0.u[0] = cvt_pk_bf16(sT[st][0].v4[0], sT[st][0].v4[1]);
      a0.u[1] = cvt_pk_bf16(sT[st][0].v4[2], sT[st][0].v4[3]);
      a0.u[2] = cvt_pk_bf16(sT[st][1].v4[0], sT[st][1].v4[1]);
      a0.u[3] = cvt_pk_bf16(sT[st][1].v4[2], sT[st][1].v4[3]);
      a1.u[0] = cvt_pk_bf16(sT[st][2].v4[0], sT[st][2].v4[1]);
      a1.u[1] = cvt_pk_bf16(sT[st][2].v4[2], sT[st][2].v4[3]);
      a1.u[2] = cvt_pk_bf16(sT[st][3].v4[0], sT[st][3].v4[1]);
      a1.u[3] = cvt_pk_bf16(sT[st][3].v4[2], sT[st][3].v4[3]);

      FragU vf00, vf01, vf10, vf11;
#pragma unroll
      for (int dt = 0; dt < 2; ++dt) {
        const int row = dt * 16 + lr;
        const int sw = (row & 7) << 3;
        FragU v0, v1;
        v0.q.lo = *(const ull*)&Vs[cur][row * 128 + ((st * 64 + 4 * g) ^ sw)];
        v0.q.hi = *(const ull*)&Vs[cur][row * 128 + ((st * 64 + 16 + 4 * g) ^ sw)];
        v1.q.lo = *(const ull*)&Vs[cur][row * 128 + ((st * 64 + 32 + 4 * g) ^ sw)];
        v1.q.hi = *(const ull*)&Vs[cur][row * 128 + ((st * 64 + 48 + 4 * g) ^ sw)];
        if (dt == 0) { vf00 = v0; vf01 = v1; } else { vf10 = v0; vf11 = v1; }
      }
      O0 = __builtin_amdgcn_mfma_f32_16x16x32_bf16(a0.v, vf00.v, O0, 0, 0, 0);
      O0 = __builtin_amdgcn_mfma_f32_16x16x32_bf16(a1.v, vf01.v, O0, 0, 0, 0);
      O1 = __builtin_amdgcn_mfma_f32_16x16x32_bf16(a0.v, vf10.v, O1, 0, 0, 0);
      O1 = __builtin_amdgcn_mfma_f32_16x16x32_bf16(a1.v, vf11.v, O1, 0, 0, 0);
    }

    if (more) {  // write-late K into next buffer
      *(int4*)&Ks[nxt][krow * 40 + koff] = ka;
    }
    asm volatile("s_waitcnt vmcnt(0) lgkmcnt(0)" ::: "memory");
    __builtin_amdgcn_sched_barrier(0);
    __builtin_amdgcn_s_barrier();
  }

  // epilogue: reduce denominator, write O
  float ssum = ssum2[0] + ssum2[1];
  ssum += __shfl_xor(ssum, 16);
  ssum += __shfl_xor(ssum, 32);
#pragma unroll
  for (int r = 0; r < 4; ++r) {
    const float sden = __shfl(ssum, 4 * g + r);
    const float inv = 1.f / sden;
    const int qo = qw0 + 4 * g + r;
    unsigned short* orow = aout + ((size_t)(b * L_ + qo)) * D_ + h * DH_;
    orow[lr]      = f2bf(O0[r] * inv);
    orow[16 + lr] = f2bf(O1[r] * inv);
  }
}

// ---------------- launch ----------------
extern "C" void kernel_launch(void* const* d_in, const int* in_sizes, int n_in,
                              void* d_out, int out_size, void* d_ws, size_t ws_size,
                              hipStream_t stream) {
  (void)in_sizes; (void)n_in; (void)out_size; (void)ws_size;
  const float* x    = (const float*)d_in[0];
  const int*   mask = (const int*)d_in[1];
  const float* Wqkv = (const float*)d_in[2];
  const float* bqkv = (const float*)d_in[3];
  const float* Wo   = (const float*)d_in[4];
  const float* bo   = (const float*)d_in[5];
  const float* ln1g = (const float*)d_in[6];
  const float* ln1b = (const float*)d_in[7];
  const float* W1   = (const float*)d_in[8];
  const float* b1   = (const float*)d_in[9];
  const float* W2   = (const float*)d_in[10];
  const float* b2   = (const float*)d_in[11];
  const float* ln2g = (const float*)d_in[12];
  const float* ln2b = (const float*)d_in[13];
  const float* relb = (const float*)d_in[14];

  size_t off = 0;
  char* wsb = (char*)d_ws;
  auto carve = [&](size_t bytes) -> void* {
    void* p = wsb + off;
    off += (bytes + 255) & ~(size_t)255;
    return p;
  };
  const size_t tokb = (size_t)B_ * L_;
  unsigned short* xb    = (unsigned short*)carve(tokb * D_ * 2);
  unsigned short* qbuf  = (unsigned short*)carve(tokb * D_ * 2);
  unsigned short* kbuf  = (unsigned short*)carve(tokb * D_ * 2);
  unsigned short* vTb   = (unsigned short*)carve(tokb * D_ * 2);
  unsigned short* attnb = (unsigned short*)carve(tokb * D_ * 2);
  unsigned short* wqkvt = (unsigned short*)carve((size_t)3 * D_ * D_ * 2);
  unsigned short* wot   = (unsigned short*)carve((size_t)D_ * D_ * 2);
  unsigned short* w1t   = (unsigned short*)carve((size_t)D_ * MLP_ * 2);
  unsigned short* w2t   = (unsigned short*)carve((size_t)D_ * MLP_ * 2);
  float*          x1    = (float*)carve(tokb * D_ * 4);
  unsigned short* x1b   = (unsigned short*)carve(tokb * D_ * 2);
  unsigned short* hbuf  = (unsigned short*)carve(tokb * MLP_ * 2);
  float*          maskfb = (float*)carve(tokb * 4);
  float*          mlob  = (float*)carve((size_t)B_ * H_ * L_ * 4);
  float*          mhib  = (float*)carve((size_t)B_ * H_ * L_ * 4);

  prep_all<<<3360, 256, 0, stream>>>(x, mask, relb, Wqkv, Wo, W1, W2,
                                     xb, maskfb, mlob, mhib,
                                     wqkvt, wot, w1t, w2t);

  // qkv: nbx=6, nby=128 -> 768 blocks = 6*8*16
  gemm_k<0, 64, 128, 6, 16><<<768, 256, 0, stream>>>(
      xb, wqkvt, bqkv, qbuf, kbuf, vTb, D_);
  // attn: 512 blocks = 8 xcd * 4 bh * 16 qblk, 128 q/block
  attn_k<<<512, 512, 0, stream>>>(
      qbuf, kbuf, vTb, maskfb, mlob, mhib, relb, attnb);
  gemmln_k<true><<<tokb / 16, 512, 0, stream>>>(
      attnb, wot, bo, x, ln1g, ln1b, x1, x1b, D_);
  // mlp1: nbx=8, nby=128 -> 1024 blocks = 8*8*16
  gemm_k<2, 64, 128, 8, 16><<<1024, 256, 0, stream>>>(
      x1b, w1t, b1, hbuf, nullptr, nullptr, D_);
  gemmln_k<false><<<tokb / 16, 512, 0, stream>>>(
      hbuf, w2t, b2, x1, ln2g, ln2b, (float*)d_out, nullptr, MLP_);
}

// Round 17
// 98.784 us; speedup vs baseline: 1.2800x; 1.0569x over previous
//
#include <hip/hip_runtime.h>

#define B_   4
#define L_   2048
#define D_   256
#define H_   8
#define DH_  32
#define MLP_ 1024
#define LOG2E 1.4426950408889634f

typedef __attribute__((ext_vector_type(8))) short  short8;
typedef __attribute__((ext_vector_type(4))) float  f32x4;
typedef __attribute__((ext_vector_type(2))) float  f32x2;
typedef unsigned long long ull;

union FragU { short8 v; struct { ull lo, hi; } q; unsigned u[4]; };
union SU { f32x4 v4; f32x2 v2[2]; };

__device__ __forceinline__ unsigned short f2bf(float f) {
  unsigned u = __float_as_uint(f);
  u += 0x7fffu + ((u >> 16) & 1u);
  return (unsigned short)(u >> 16);
}

__device__ __forceinline__ ull pack4(float a, float b, float c, float d) {
  return (ull)f2bf(a) | ((ull)f2bf(b) << 16) | ((ull)f2bf(c) << 32) | ((ull)f2bf(d) << 48);
}

__device__ __forceinline__ unsigned cvt_pk_bf16(float lo, float hi) {
  unsigned r;
  asm("v_cvt_pk_bf16_f32 %0, %1, %2" : "=v"(r) : "v"(lo), "v"(hi));
  return r;
}

// packed f32 add (legal VOP3P on gfx950; pk_max is NOT)
__device__ __forceinline__ f32x2 pk_add(f32x2 a, f32x2 b) {
  f32x2 r; asm("v_pk_add_f32 %0, %1, %2" : "=v"(r) : "v"(a), "v"(b)); return r;
}

__device__ __forceinline__ float fexp2(float x) {
#if __has_builtin(__builtin_amdgcn_exp2f)
  return __builtin_amdgcn_exp2f(x);
#else
  return exp2f(x);
#endif
}

#define GLL16(gp, lp) __builtin_amdgcn_global_load_lds( \
    (const __attribute__((address_space(1))) void*)(gp), \
    (__attribute__((address_space(3))) void*)(lp), 16, 0, 0)

// ---------------- all input prep, ONE launch ----------------
__launch_bounds__(256)
__global__ void prep_all(const float* __restrict__ x,
                         const int* __restrict__ mask, const float* __restrict__ relb,
                         const float* __restrict__ Wqkv, const float* __restrict__ Wo,
                         const float* __restrict__ W1, const float* __restrict__ W2,
                         unsigned short* __restrict__ xb,
                         float* __restrict__ maskf,
                         float* __restrict__ mlo, float* __restrict__ mhi,
                         unsigned short* __restrict__ wqkvt, unsigned short* __restrict__ wot,
                         unsigned short* __restrict__ w1t, unsigned short* __restrict__ w2t) {
  __shared__ float tile[32][33];
  const int bid = blockIdx.x;
  if (bid < 768) {
    const float* src; unsigned short* dst; int R, C, tr, tc;
    if (bid < 192)      { src = Wqkv; dst = wqkvt; R = 256;  C = 768;  tr = bid / 24;          tc = bid % 24; }
    else if (bid < 256) { src = Wo;   dst = wot;   R = 256;  C = 256;  tr = (bid - 192) >> 3;  tc = (bid - 192) & 7; }
    else if (bid < 512) { src = W1;   dst = w1t;   R = 256;  C = 1024; tr = (bid - 256) >> 5;  tc = (bid - 256) & 31; }
    else                { src = W2;   dst = w2t;   R = 1024; C = 256;  tr = (bid - 512) >> 3;  tc = (bid - 512) & 7; }
    const int tx = threadIdx.x & 31, ty = threadIdx.x >> 5;
#pragma unroll
    for (int i = 0; i < 4; ++i) {
      const int r = tr * 32 + ty + i * 8;
      tile[ty + i * 8][tx] = src[(size_t)r * C + tc * 32 + tx];
    }
    __syncthreads();
#pragma unroll
    for (int i = 0; i < 4; ++i) {
      const int c = tc * 32 + ty + i * 8;
      dst[(size_t)c * R + tr * 32 + tx] = f2bf(tile[tx][ty + i * 8]);
    }
  } else {
    const int i = (bid - 768) * 256 + threadIdx.x;
    if (i < 524288) {            // x: 2,097,152 floats, 4 per thread
      const float4 v = *(const float4*)(x + (size_t)i * 4);
      *(ull*)(xb + (size_t)i * 4) = pack4(v.x, v.y, v.z, v.w);
    } else if (i < 532480) {     // raw mask -> additive float [B,L]
      const int j = i - 524288;
      maskf[j] = mask[j] ? -1e9f : 0.f;
    } else {                     // pre-biased far-field tables [B*H][L], lo and hi
      const int j2 = i - 532480;
      const int t = j2 >> 16, idx = j2 & 65535;
      const int bh = idx >> 11, j = idx & 2047;
      const int bq = bh >> 3, h = bh & 7;
      const float base = mask[bq * L_ + j] ? -1e9f : 0.f;
      const float bias = relb[(t ? 32 * H_ : 0) + h] * LOG2E;
      (t ? mhi : mlo)[idx] = base + bias;
    }
  }
}

// ---------------- GEMM (dbuf, counted vmcnt, XCD-swizzled 1D grid) ----------------
// Fragments: shared sigma(g,i)=8g+i per 32-wide k-slice on BOTH operands ->
// one 16B-aligned ds_read_b128 per fragment (2-way bank alias, free).
template <int MODE, int TM, int TN, int NBX, int BYG>
__launch_bounds__(256)
__global__ void gemm_k(const unsigned short* __restrict__ A,
                       const unsigned short* __restrict__ Bt,
                       const float* __restrict__ bias,
                       unsigned short* __restrict__ outb0,
                       unsigned short* __restrict__ outb1,
                       unsigned short* __restrict__ outb2,
                       int K)
{
  constexpr int MI = TM / 32, NI = TN / 32;
  __shared__ alignas(16) unsigned short As[2][TM * 64];
  __shared__ alignas(16) unsigned short Bs[2][TN * 64];
  const int tid  = threadIdx.x;
  const int lane = tid & 63, wv = tid >> 6;
  const int wr = wv >> 1, wc = wv & 1;
  const int lr = lane & 15, g = lane >> 4;
  const int bid = blockIdx.x;
  const int xcd = bid & 7, ii = bid >> 3;
  const int by = xcd * BYG + ii / NBX;
  const int bx = ii % NBX;
  const int m0 = by * TM, n0 = bx * TN;
  const int l8 = lane >> 3, jj = lane & 7;

  auto stage = [&](int buf, int k0) {
#pragma unroll
    for (int i = 0; i < MI; ++i) {
      const int row = i * 32 + wv * 8 + l8;
      GLL16(A + (size_t)(m0 + row) * K + k0 + ((jj ^ (row & 7)) * 8),
            &As[buf][i * 2048 + wv * 512]);
    }
#pragma unroll
    for (int i = 0; i < NI; ++i) {
      const int row = i * 32 + wv * 8 + l8;
      GLL16(Bt + (size_t)(n0 + row) * K + k0 + ((jj ^ (row & 7)) * 8),
            &Bs[buf][i * 2048 + wv * 512]);
    }
  };

  f32x4 acc[MI][NI];
#pragma unroll
  for (int i = 0; i < MI; ++i)
#pragma unroll
    for (int j = 0; j < NI; ++j) acc[i][j] = (f32x4)(0.f);

  stage(0, 0);
  for (int k0 = 0; k0 < K; k0 += 64) {
    const int cur = (k0 >> 6) & 1;
    if (k0 + 64 < K) {
      stage(cur ^ 1, k0 + 64);
      asm volatile("s_waitcnt vmcnt(%0)" :: "n"(MI + NI) : "memory");
    } else {
      asm volatile("s_waitcnt vmcnt(0)" ::: "memory");
    }
    __builtin_amdgcn_sched_barrier(0);
    __builtin_amdgcn_s_barrier();
#pragma unroll
    for (int kk = 0; kk < 2; ++kk) {
      FragU af[MI], bf[NI];
#pragma unroll
      for (int mi = 0; mi < MI; ++mi) {
        const int row = wr * (TM / 2) + mi * 16 + lr;
        const int sw = (row & 7) << 3;
        af[mi].v = *(const short8*)&As[cur][row * 64 + ((kk * 32 + 8 * g) ^ sw)];
      }
#pragma unroll
      for (int ni = 0; ni < NI; ++ni) {
        const int row = wc * (TN / 2) + ni * 16 + lr;
        const int sw = (row & 7) << 3;
        bf[ni].v = *(const short8*)&Bs[cur][row * 64 + ((kk * 32 + 8 * g) ^ sw)];
      }
#pragma unroll
      for (int mi = 0; mi < MI; ++mi)
#pragma unroll
        for (int ni = 0; ni < NI; ++ni)
          acc[mi][ni] = __builtin_amdgcn_mfma_f32_16x16x32_bf16(af[mi].v, bf[ni].v, acc[mi][ni], 0, 0, 0);
    }
    asm volatile("s_waitcnt lgkmcnt(0)" ::: "memory");
    __builtin_amdgcn_sched_barrier(0);
    __builtin_amdgcn_s_barrier();
  }

#pragma unroll
  for (int mi = 0; mi < MI; ++mi) {
#pragma unroll
    for (int ni = 0; ni < NI; ++ni) {
      const int n = n0 + wc * (TN / 2) + ni * 16 + lr;
      const float bv = bias[n];
#pragma unroll
      for (int r = 0; r < 4; ++r) {
        const int m = m0 + wr * (TM / 2) + mi * 16 + 4 * g + r;
        float val = acc[mi][ni][r] + bv;
        if constexpr (MODE == 0) {
          const int s = n >> 8, hh = (n >> 5) & 7, dh = n & 31;
          const int bb = m >> 11, l = m & (L_ - 1);
          if (s == 0) {
            outb0[((size_t)(bb * H_ + hh) * L_ + l) * DH_ + dh] =
                f2bf(val * (0.17677669529663687f * LOG2E));
          } else if (s == 1) {
            outb1[((size_t)(bb * H_ + hh) * L_ + l) * DH_ + dh] = f2bf(val);
          } else {
            outb2[((size_t)(bb * H_ + hh) * DH_ + dh) * L_ + l] = f2bf(val);
          }
        } else {
          outb0[(size_t)m * MLP_ + n] = f2bf(fmaxf(val, 0.f));
        }
      }
    }
  }
}

// ---------------- fused GEMM + residual + LayerNorm (LDS-staged, TN=256, TM=16) ----------------
template <bool WRITE_BF>
__launch_bounds__(512)
__global__ void gemmln_k(const unsigned short* __restrict__ A,
                         const unsigned short* __restrict__ Bt,
                         const float* __restrict__ bias,
                         const float* __restrict__ resid,
                         const float* __restrict__ lng,
                         const float* __restrict__ lnb,
                         float* __restrict__ outf,
                         unsigned short* __restrict__ outb,
                         int K)
{
  __shared__ alignas(16) unsigned short As[2][16 * 64];
  __shared__ alignas(16) unsigned short Bs[2][256 * 64];
  __shared__ float rsum[8][16], rsq[8][16], rmu[16], rrstd[16];
  const int tid  = threadIdx.x;
  const int lane = tid & 63, wv = tid >> 6;
  const int lr = lane & 15, g = lane >> 4;
  const int m0 = blockIdx.x * 16;
  const int l8 = lane >> 3, jj = lane & 7;

  auto stage = [&](int buf, int k0) {
    if (wv < 2) {
      const int row = wv * 8 + l8;
      GLL16(A + (size_t)(m0 + row) * K + k0 + ((jj ^ (row & 7)) * 8),
            &As[buf][wv * 512]);
    }
#pragma unroll
    for (int i = 0; i < 4; ++i) {
      const int n = i * 64 + wv * 8 + l8;
      GLL16(Bt + (size_t)n * K + k0 + ((jj ^ (n & 7)) * 8),
            &Bs[buf][i * 4096 + wv * 512]);
    }
  };

  f32x4 acc[2];
  acc[0] = (f32x4)(0.f); acc[1] = (f32x4)(0.f);

  stage(0, 0);
  for (int k0 = 0; k0 < K; k0 += 64) {
    const int cur = (k0 >> 6) & 1;
    if (k0 + 64 < K) {
      stage(cur ^ 1, k0 + 64);
      asm volatile("s_waitcnt vmcnt(4)" ::: "memory");
    } else {
      asm volatile("s_waitcnt vmcnt(0)" ::: "memory");
    }
    __builtin_amdgcn_sched_barrier(0);
    __builtin_amdgcn_s_barrier();
#pragma unroll
    for (int kk = 0; kk < 2; ++kk) {
      FragU af, bf[2];
      {
        const int sw = (lr & 7) << 3;
        af.v = *(const short8*)&As[cur][lr * 64 + ((kk * 32 + 8 * g) ^ sw)];
      }
#pragma unroll
      for (int ni = 0; ni < 2; ++ni) {
        const int row = wv * 32 + ni * 16 + lr;
        const int sw = (row & 7) << 3;
        bf[ni].v = *(const short8*)&Bs[cur][row * 64 + ((kk * 32 + 8 * g) ^ sw)];
      }
#pragma unroll
      for (int ni = 0; ni < 2; ++ni)
        acc[ni] = __builtin_amdgcn_mfma_f32_16x16x32_bf16(af.v, bf[ni].v, acc[ni], 0, 0, 0);
    }
    asm volatile("s_waitcnt lgkmcnt(0)" ::: "memory");
    __builtin_amdgcn_sched_barrier(0);
    __builtin_amdgcn_s_barrier();
  }

  float g2[2], b2[2], bias2[2];
  int col[2];
#pragma unroll
  for (int ni = 0; ni < 2; ++ni) {
    col[ni] = wv * 32 + ni * 16 + lr;
    g2[ni] = lng[col[ni]]; b2[ni] = lnb[col[ni]]; bias2[ni] = bias[col[ni]];
  }
  float vals[2][4];
#pragma unroll
  for (int r = 0; r < 4; ++r) {
    const int row = 4 * g + r;
    float s = 0.f, q = 0.f;
#pragma unroll
    for (int ni = 0; ni < 2; ++ni) {
      float v = acc[ni][r] + bias2[ni] + resid[(size_t)(m0 + row) * D_ + col[ni]];
      vals[ni][r] = v; s += v; q += v * v;
    }
#pragma unroll
    for (int off = 1; off < 16; off <<= 1) {
      s += __shfl_xor(s, off); q += __shfl_xor(q, off);
    }
    if (lr == 0) { rsum[wv][row] = s; rsq[wv][row] = q; }
  }
  __syncthreads();
  if (tid < 16) {
    float s = 0.f, q = 0.f;
#pragma unroll
    for (int w = 0; w < 8; ++w) { s += rsum[w][tid]; q += rsq[w][tid]; }
    const float mu = s * (1.f / D_);
    rmu[tid] = mu;
    rrstd[tid] = rsqrtf(q * (1.f / D_) - mu * mu + 1e-5f);
  }
  __syncthreads();
#pragma unroll
  for (int r = 0; r < 4; ++r) {
    const int row = 4 * g + r;
    const float mu = rmu[row], rs = rrstd[row];
#pragma unroll
    for (int ni = 0; ni < 2; ++ni) {
      const float o = (vals[ni][r] - mu) * rs * g2[ni] + b2[ni];
      const size_t idx = (size_t)(m0 + row) * D_ + col[ni];
      outf[idx] = o;
      if constexpr (WRITE_BF) outb[idx] = f2bf(o);
    }
  }
}

// ---------------- flash attention (R16 structure, unchanged) ----------------
__launch_bounds__(512)
__global__ void attn_k(const unsigned short* __restrict__ qb,
                       const unsigned short* __restrict__ kp,
                       const unsigned short* __restrict__ vT,
                       const float* __restrict__ maskf,
                       const float* __restrict__ mlo,
                       const float* __restrict__ mhi,
                       const float* __restrict__ relb,
                       unsigned short* __restrict__ aout)
{
  __shared__ alignas(16) unsigned short Ks[2][128 * 40];   // padded rows (80B)
  __shared__ alignas(16) unsigned short Vs[2][32 * 128];   // XOR-swizzled
  __shared__ alignas(16) float biasv[36];
  const int tid = threadIdx.x;
  const int lane = tid & 63, wv = tid >> 6;                // wv in 0..7
  const int lr = lane & 15, g = lane >> 4;
  // XCD-aware decode: 512 blocks = 8 xcd * 4 bh * 16 qblk (bijective)
  const int bid = blockIdx.x;
  const int ii = bid >> 3;
  const int bh = (bid & 7) * 4 + (ii >> 4);
  const int qblk = ii & 15;
  const int b = bh >> 3, h = bh & 7;
  const size_t bhoff = (size_t)bh * (L_ * DH_);
  if (tid < 33) biasv[tid] = relb[tid * H_ + h] * LOG2E;
  const int qw0 = qblk * 128 + wv * 16;

  FragU qf;
  qf.v = *(const short8*)(qb + bhoff + (size_t)(qw0 + lr) * DH_ + 8 * g);

  f32x4 O0 = (f32x4)(0.f), O1 = (f32x4)(0.f);
  f32x2 ssum2 = {0.f, 0.f};
  const f32x4 z4 = (f32x4)(0.f);
  const int krow = tid >> 2, koff = (tid & 3) * 8;         // 512 thr: 16B/thread
  const float* mtl = mlo + (size_t)bh * L_ + 4 * g;
  const float* mth = mhi + (size_t)bh * L_ + 4 * g;
  const float* mbn = maskf + (size_t)b * L_ + 4 * g;

  // prologue: stage chunk 0 into buffers[0]
  {
    const int4 ka = *(const int4*)(kp + bhoff + (size_t)krow * DH_ + koff);
    const int d = wv * 4 + (lane >> 4);
    GLL16(vT + ((size_t)bh * DH_ + d) * L_ + (((lane & 15) * 8) ^ ((d & 7) * 8)),
          &Vs[0][wv * 512]);
    *(int4*)&Ks[0][krow * 40 + koff] = ka;
    asm volatile("s_waitcnt vmcnt(0) lgkmcnt(0)" ::: "memory");
    __builtin_amdgcn_s_barrier();
  }

#pragma unroll 2
  for (int ch = 0; ch < 16; ++ch) {
    const int cur = ch & 1, nxt = cur ^ 1;
    const int kv = ch * 128;
    const bool more = ch < 15;
    int4 ka = {0, 0, 0, 0};
    if (more) {   // prefetch chunk ch+1: K->regs, V->LDS[nxt] via gll16
      ka = *(const int4*)(kp + bhoff + (size_t)(kv + 128 + krow) * DH_ + koff);
      const int d = wv * 4 + (lane >> 4);
      GLL16(vT + ((size_t)bh * DH_ + d) * L_ + kv + 128 + (((lane & 15) * 8) ^ ((d & 7) * 8)),
            &Vs[nxt][wv * 512]);
    }

    // hoisted QK phase: both sub-tiles' K frags (one b128 each) + 8 MFMAs
    SU sT[2][4];
#pragma unroll
    for (int st = 0; st < 2; ++st) {
      const unsigned short* KsC = &Ks[cur][st * 64 * 40];
#pragma unroll
      for (int jt = 0; jt < 4; ++jt) {
        FragU kf;
        kf.v = *(const short8*)&KsC[(jt * 16 + lr) * 40 + 8 * g];
        sT[st][jt].v4 = __builtin_amdgcn_mfma_f32_16x16x32_bf16(kf.v, qf.v, z4, 0, 0, 0);
      }
    }

#pragma unroll
    for (int st = 0; st < 2; ++st) {
      const int j0 = kv + st * 64;
      const int dlt = j0 - qw0;
      if (dlt >= 32 || dlt <= -80) {          // far field: pre-biased table
        const float* mt = (dlt > 0) ? mth : mtl;
#pragma unroll
        for (int jt = 0; jt < 4; ++jt) {
          SU mk; mk.v4 = *(const f32x4*)(mt + j0 + jt * 16);
          sT[st][jt].v2[0] = pk_add(sT[st][jt].v2[0], mk.v2[0]);
          sT[st][jt].v2[1] = pk_add(sT[st][jt].v2[1], mk.v2[1]);
        }
      } else {                                 // near field (2 of 32 sub-tiles)
#pragma unroll
        for (int jt = 0; jt < 4; ++jt)
#pragma unroll
          for (int r = 0; r < 4; ++r) {
            int rel = j0 + jt * 16 + 4 * g + r - (qw0 + lr);
            rel = rel < -16 ? -16 : (rel > 16 ? 16 : rel);
            sT[st][jt].v4[r] += biasv[rel + 16] + mbn[j0 + jt * 16 + r];
          }
      }
      // max-free: p = exp2(s) directly (masked -> 0)
#pragma unroll
      for (int jt = 0; jt < 4; ++jt)
#pragma unroll
        for (int r = 0; r < 4; ++r)
          sT[st][jt].v4[r] = fexp2(sT[st][jt].v4[r]);
      // packed partial-sum accumulate
      const f32x2 s01 = pk_add(sT[st][0].v2[0], sT[st][0].v2[1]);
      const f32x2 s23 = pk_add(sT[st][1].v2[0], sT[st][1].v2[1]);
      const f32x2 s45 = pk_add(sT[st][2].v2[0], sT[st][2].v2[1]);
      const f32x2 s67 = pk_add(sT[st][3].v2[0], sT[st][3].v2[1]);
      ssum2 = pk_add(ssum2, pk_add(pk_add(s01, s23), pk_add(s45, s67)));

      FragU a0, a1;
      a0.u[0] = cvt_pk_bf16(sT[st][0].v4[0], sT[st][0].v4[1]);
      a0.u[1] = cvt_pk_bf16(sT[st][0].v4[2], sT[st][0].v4[3]);
      a0.u[2] = cvt_pk_bf16(sT[st][1].v4[0], sT[st][1].v4[1]);
      a0.u[3] = cvt_pk_bf16(sT[st][1].v4[2], sT[st][1].v4[3]);
      a1.u[0] = cvt_pk_bf16(sT[st][2].v4[0], sT[st][2].v4[1]);
      a1.u[1] = cvt_pk_bf16(sT[st][2].v4[2], sT[st][2].v4[3]);
      a1.u[2] = cvt_pk_bf16(sT[st][3].v4[0], sT[st][3].v4[1]);
      a1.u[3] = cvt_pk_bf16(sT[st][3].v4[2], sT[st][3].v4[3]);

      FragU vf00, vf01, vf10, vf11;
#pragma unroll
      for (int dt = 0; dt < 2; ++dt) {
        const int row = dt * 16 + lr;
        const int sw = (row & 7) << 3;
        FragU v0, v1;
        v0.q.lo = *(const ull*)&Vs[cur][row * 128 + ((st * 64 + 4 * g) ^ sw)];
        v0.q.hi = *(const ull*)&Vs[cur][row * 128 + ((st * 64 + 16 + 4 * g) ^ sw)];
        v1.q.lo = *(const ull*)&Vs[cur][row * 128 + ((st * 64 + 32 + 4 * g) ^ sw)];
        v1.q.hi = *(const ull*)&Vs[cur][row * 128 + ((st * 64 + 48 + 4 * g) ^ sw)];
        if (dt == 0) { vf00 = v0; vf01 = v1; } else { vf10 = v0; vf11 = v1; }
      }
      O0 = __builtin_amdgcn_mfma_f32_16x16x32_bf16(a0.v, vf00.v, O0, 0, 0, 0);
      O0 = __builtin_amdgcn_mfma_f32_16x16x32_bf16(a1.v, vf01.v, O0, 0, 0, 0);
      O1 = __builtin_amdgcn_mfma_f32_16x16x32_bf16(a0.v, vf10.v, O1, 0, 0, 0);
      O1 = __builtin_amdgcn_mfma_f32_16x16x32_bf16(a1.v, vf11.v, O1, 0, 0, 0);
    }

    if (more) {  // write-late K into next buffer
      *(int4*)&Ks[nxt][krow * 40 + koff] = ka;
    }
    asm volatile("s_waitcnt vmcnt(0) lgkmcnt(0)" ::: "memory");
    __builtin_amdgcn_sched_barrier(0);
    __builtin_amdgcn_s_barrier();
  }

  // epilogue: reduce denominator, write O
  float ssum = ssum2[0] + ssum2[1];
  ssum += __shfl_xor(ssum, 16);
  ssum += __shfl_xor(ssum, 32);
#pragma unroll
  for (int r = 0; r < 4; ++r) {
    const float sden = __shfl(ssum, 4 * g + r);
    const float inv = 1.f / sden;
    const int qo = qw0 + 4 * g + r;
    unsigned short* orow = aout + ((size_t)(b * L_ + qo)) * D_ + h * DH_;
    orow[lr]      = f2bf(O0[r] * inv);
    orow[16 + lr] = f2bf(O1[r] * inv);
  }
}

// ---------------- launch ----------------
extern "C" void kernel_launch(void* const* d_in, const int* in_sizes, int n_in,
                              void* d_out, int out_size, void* d_ws, size_t ws_size,
                              hipStream_t stream) {
  (void)in_sizes; (void)n_in; (void)out_size; (void)ws_size;
  const float* x    = (const float*)d_in[0];
  const int*   mask = (const int*)d_in[1];
  const float* Wqkv = (const float*)d_in[2];
  const float* bqkv = (const float*)d_in[3];
  const float* Wo   = (const float*)d_in[4];
  const float* bo   = (const float*)d_in[5];
  const float* ln1g = (const float*)d_in[6];
  const float* ln1b = (const float*)d_in[7];
  const float* W1   = (const float*)d_in[8];
  const float* b1   = (const float*)d_in[9];
  const float* W2   = (const float*)d_in[10];
  const float* b2   = (const float*)d_in[11];
  const float* ln2g = (const float*)d_in[12];
  const float* ln2b = (const float*)d_in[13];
  const float* relb = (const float*)d_in[14];

  size_t off = 0;
  char* wsb = (char*)d_ws;
  auto carve = [&](size_t bytes) -> void* {
    void* p = wsb + off;
    off += (bytes + 255) & ~(size_t)255;
    return p;
  };
  const size_t tokb = (size_t)B_ * L_;
  unsigned short* xb    = (unsigned short*)carve(tokb * D_ * 2);
  unsigned short* qbuf  = (unsigned short*)carve(tokb * D_ * 2);
  unsigned short* kbuf  = (unsigned short*)carve(tokb * D_ * 2);
  unsigned short* vTb   = (unsigned short*)carve(tokb * D_ * 2);
  unsigned short* attnb = (unsigned short*)carve(tokb * D_ * 2);
  unsigned short* wqkvt = (unsigned short*)carve((size_t)3 * D_ * D_ * 2);
  unsigned short* wot   = (unsigned short*)carve((size_t)D_ * D_ * 2);
  unsigned short* w1t   = (unsigned short*)carve((size_t)D_ * MLP_ * 2);
  unsigned short* w2t   = (unsigned short*)carve((size_t)D_ * MLP_ * 2);
  float*          x1    = (float*)carve(tokb * D_ * 4);
  unsigned short* x1b   = (unsigned short*)carve(tokb * D_ * 2);
  unsigned short* hbuf  = (unsigned short*)carve(tokb * MLP_ * 2);
  float*          maskfb = (float*)carve(tokb * 4);
  float*          mlob  = (float*)carve((size_t)B_ * H_ * L_ * 4);
  float*          mhib  = (float*)carve((size_t)B_ * H_ * L_ * 4);

  prep_all<<<3360, 256, 0, stream>>>(x, mask, relb, Wqkv, Wo, W1, W2,
                                     xb, maskfb, mlob, mhib,
                                     wqkvt, wot, w1t, w2t);

  // qkv: nbx=6, nby=128 -> 768 blocks = 6*8*16
  gemm_k<0, 64, 128, 6, 16><<<768, 256, 0, stream>>>(
      xb, wqkvt, bqkv, qbuf, kbuf, vTb, D_);
  // attn: 512 blocks = 8 xcd * 4 bh * 16 qblk, 128 q/block
  attn_k<<<512, 512, 0, stream>>>(
      qbuf, kbuf, vTb, maskfb, mlob, mhib, relb, attnb);
  gemmln_k<true><<<tokb / 16, 512, 0, stream>>>(
      attnb, wot, bo, x, ln1g, ln1b, x1, x1b, D_);
  // mlp1: nbx=8, nby=128 -> 1024 blocks = 8*8*16
  gemm_k<2, 64, 128, 8, 16><<<1024, 256, 0, stream>>>(
      x1b, w1t, b1, hbuf, nullptr, nullptr, D_);
  gemmln_k<false><<<tokb / 16, 512, 0, stream>>>(
      hbuf, w2t, b2, x1, ln2g, ln2b, (float*)d_out, nullptr, MLP_);
}

// Round 18
// 95.951 us; speedup vs baseline: 1.3178x; 1.0295x over previous
//
#include <hip/hip_runtime.h>

#define B_   4
#define L_   2048
#define D_   256
#define H_   8
#define DH_  32
#define MLP_ 1024
#define LOG2E 1.4426950408889634f

typedef __attribute__((ext_vector_type(8))) short  short8;
typedef __attribute__((ext_vector_type(4))) float  f32x4;
typedef __attribute__((ext_vector_type(2))) float  f32x2;
typedef unsigned long long ull;

union FragU { short8 v; struct { ull lo, hi; } q; unsigned u[4]; };
union SU { f32x4 v4; f32x2 v2[2]; };

__device__ __forceinline__ unsigned short f2bf(float f) {
  unsigned u = __float_as_uint(f);
  u += 0x7fffu + ((u >> 16) & 1u);
  return (unsigned short)(u >> 16);
}

__device__ __forceinline__ ull pack4(float a, float b, float c, float d) {
  return (ull)f2bf(a) | ((ull)f2bf(b) << 16) | ((ull)f2bf(c) << 32) | ((ull)f2bf(d) << 48);
}

__device__ __forceinline__ unsigned cvt_pk_bf16(float lo, float hi) {
  unsigned r;
  asm("v_cvt_pk_bf16_f32 %0, %1, %2" : "=v"(r) : "v"(lo), "v"(hi));
  return r;
}

// packed f32 add (legal VOP3P on gfx950; pk_max is NOT)
__device__ __forceinline__ f32x2 pk_add(f32x2 a, f32x2 b) {
  f32x2 r; asm("v_pk_add_f32 %0, %1, %2" : "=v"(r) : "v"(a), "v"(b)); return r;
}

__device__ __forceinline__ float fexp2(float x) {
#if __has_builtin(__builtin_amdgcn_exp2f)
  return __builtin_amdgcn_exp2f(x);
#else
  return exp2f(x);
#endif
}

#define GLL16(gp, lp) __builtin_amdgcn_global_load_lds( \
    (const __attribute__((address_space(1))) void*)(gp), \
    (__attribute__((address_space(3))) void*)(lp), 16, 0, 0)

// ---------------- all input prep, ONE launch ----------------
__launch_bounds__(256)
__global__ void prep_all(const float* __restrict__ x,
                         const int* __restrict__ mask, const float* __restrict__ relb,
                         const float* __restrict__ Wqkv, const float* __restrict__ Wo,
                         const float* __restrict__ W1, const float* __restrict__ W2,
                         unsigned short* __restrict__ xb,
                         float* __restrict__ maskf,
                         float* __restrict__ mlo, float* __restrict__ mhi,
                         unsigned short* __restrict__ wqkvt, unsigned short* __restrict__ wot,
                         unsigned short* __restrict__ w1t, unsigned short* __restrict__ w2t) {
  __shared__ float tile[32][33];
  const int bid = blockIdx.x;
  if (bid < 768) {
    const float* src; unsigned short* dst; int R, C, tr, tc;
    if (bid < 192)      { src = Wqkv; dst = wqkvt; R = 256;  C = 768;  tr = bid / 24;          tc = bid % 24; }
    else if (bid < 256) { src = Wo;   dst = wot;   R = 256;  C = 256;  tr = (bid - 192) >> 3;  tc = (bid - 192) & 7; }
    else if (bid < 512) { src = W1;   dst = w1t;   R = 256;  C = 1024; tr = (bid - 256) >> 5;  tc = (bid - 256) & 31; }
    else                { src = W2;   dst = w2t;   R = 1024; C = 256;  tr = (bid - 512) >> 3;  tc = (bid - 512) & 7; }
    const int tx = threadIdx.x & 31, ty = threadIdx.x >> 5;
#pragma unroll
    for (int i = 0; i < 4; ++i) {
      const int r = tr * 32 + ty + i * 8;
      tile[ty + i * 8][tx] = src[(size_t)r * C + tc * 32 + tx];
    }
    __syncthreads();
#pragma unroll
    for (int i = 0; i < 4; ++i) {
      const int c = tc * 32 + ty + i * 8;
      dst[(size_t)c * R + tr * 32 + tx] = f2bf(tile[tx][ty + i * 8]);
    }
  } else {
    const int i = (bid - 768) * 256 + threadIdx.x;
    if (i < 524288) {            // x: 2,097,152 floats, 4 per thread
      const float4 v = *(const float4*)(x + (size_t)i * 4);
      *(ull*)(xb + (size_t)i * 4) = pack4(v.x, v.y, v.z, v.w);
    } else if (i < 532480) {     // raw mask -> additive float [B,L]
      const int j = i - 524288;
      maskf[j] = mask[j] ? -1e9f : 0.f;
    } else {                     // pre-biased far-field tables [B*H][L], lo and hi
      const int j2 = i - 532480;
      const int t = j2 >> 16, idx = j2 & 65535;
      const int bh = idx >> 11, j = idx & 2047;
      const int bq = bh >> 3, h = bh & 7;
      const float base = mask[bq * L_ + j] ? -1e9f : 0.f;
      const float bias = relb[(t ? 32 * H_ : 0) + h] * LOG2E;
      (t ? mhi : mlo)[idx] = base + bias;
    }
  }
}

// ---------------- GEMM (dbuf, counted vmcnt, XCD-swizzled 1D grid) ----------------
// Fragments: shared sigma(g,i)=8g+i per 32-wide k-slice -> one ds_read_b128 each.
// MODE 0 vT epilogue: 4 consecutive l values per fragment -> one packed 8B store.
template <int MODE, int TM, int TN, int NBX, int BYG>
__launch_bounds__(256)
__global__ void gemm_k(const unsigned short* __restrict__ A,
                       const unsigned short* __restrict__ Bt,
                       const float* __restrict__ bias,
                       unsigned short* __restrict__ outb0,
                       unsigned short* __restrict__ outb1,
                       unsigned short* __restrict__ outb2,
                       int K)
{
  constexpr int MI = TM / 32, NI = TN / 32;
  __shared__ alignas(16) unsigned short As[2][TM * 64];
  __shared__ alignas(16) unsigned short Bs[2][TN * 64];
  const int tid  = threadIdx.x;
  const int lane = tid & 63, wv = tid >> 6;
  const int wr = wv >> 1, wc = wv & 1;
  const int lr = lane & 15, g = lane >> 4;
  const int bid = blockIdx.x;
  const int xcd = bid & 7, ii = bid >> 3;
  const int by = xcd * BYG + ii / NBX;
  const int bx = ii % NBX;
  const int m0 = by * TM, n0 = bx * TN;
  const int l8 = lane >> 3, jj = lane & 7;

  auto stage = [&](int buf, int k0) {
#pragma unroll
    for (int i = 0; i < MI; ++i) {
      const int row = i * 32 + wv * 8 + l8;
      GLL16(A + (size_t)(m0 + row) * K + k0 + ((jj ^ (row & 7)) * 8),
            &As[buf][i * 2048 + wv * 512]);
    }
#pragma unroll
    for (int i = 0; i < NI; ++i) {
      const int row = i * 32 + wv * 8 + l8;
      GLL16(Bt + (size_t)(n0 + row) * K + k0 + ((jj ^ (row & 7)) * 8),
            &Bs[buf][i * 2048 + wv * 512]);
    }
  };

  f32x4 acc[MI][NI];
#pragma unroll
  for (int i = 0; i < MI; ++i)
#pragma unroll
    for (int j = 0; j < NI; ++j) acc[i][j] = (f32x4)(0.f);

  stage(0, 0);
  for (int k0 = 0; k0 < K; k0 += 64) {
    const int cur = (k0 >> 6) & 1;
    if (k0 + 64 < K) {
      stage(cur ^ 1, k0 + 64);
      asm volatile("s_waitcnt vmcnt(%0)" :: "n"(MI + NI) : "memory");
    } else {
      asm volatile("s_waitcnt vmcnt(0)" ::: "memory");
    }
    __builtin_amdgcn_sched_barrier(0);
    __builtin_amdgcn_s_barrier();
#pragma unroll
    for (int kk = 0; kk < 2; ++kk) {
      FragU af[MI], bf[NI];
#pragma unroll
      for (int mi = 0; mi < MI; ++mi) {
        const int row = wr * (TM / 2) + mi * 16 + lr;
        const int sw = (row & 7) << 3;
        af[mi].v = *(const short8*)&As[cur][row * 64 + ((kk * 32 + 8 * g) ^ sw)];
      }
#pragma unroll
      for (int ni = 0; ni < NI; ++ni) {
        const int row = wc * (TN / 2) + ni * 16 + lr;
        const int sw = (row & 7) << 3;
        bf[ni].v = *(const short8*)&Bs[cur][row * 64 + ((kk * 32 + 8 * g) ^ sw)];
      }
#pragma unroll
      for (int mi = 0; mi < MI; ++mi)
#pragma unroll
        for (int ni = 0; ni < NI; ++ni)
          acc[mi][ni] = __builtin_amdgcn_mfma_f32_16x16x32_bf16(af[mi].v, bf[ni].v, acc[mi][ni], 0, 0, 0);
    }
    asm volatile("s_waitcnt lgkmcnt(0)" ::: "memory");
    __builtin_amdgcn_sched_barrier(0);
    __builtin_amdgcn_s_barrier();
  }

#pragma unroll
  for (int mi = 0; mi < MI; ++mi) {
#pragma unroll
    for (int ni = 0; ni < NI; ++ni) {
      const int n = n0 + wc * (TN / 2) + ni * 16 + lr;
      const float bv = bias[n];
      const int mrow = m0 + wr * (TM / 2) + mi * 16 + 4 * g;
      if constexpr (MODE == 0) {
        const int s = n >> 8, hh = (n >> 5) & 7, dh = n & 31;
        const int bb = m0 >> 11;                 // TM=64 tile never crosses a batch
        if (s == 2) {                            // vT: 4 consecutive l -> one 8B store
          const int l0 = mrow & (L_ - 1);
          *(ull*)&outb2[((size_t)(bb * H_ + hh) * DH_ + dh) * L_ + l0] =
              pack4(acc[mi][ni][0] + bv, acc[mi][ni][1] + bv,
                    acc[mi][ni][2] + bv, acc[mi][ni][3] + bv);
        } else {
#pragma unroll
          for (int r = 0; r < 4; ++r) {
            const int l = (mrow + r) & (L_ - 1);
            const float val = acc[mi][ni][r] + bv;
            if (s == 0)
              outb0[((size_t)(bb * H_ + hh) * L_ + l) * DH_ + dh] =
                  f2bf(val * (0.17677669529663687f * LOG2E));
            else
              outb1[((size_t)(bb * H_ + hh) * L_ + l) * DH_ + dh] = f2bf(val);
          }
        }
      } else {
#pragma unroll
        for (int r = 0; r < 4; ++r)
          outb0[(size_t)(mrow + r) * MLP_ + n] = f2bf(fmaxf(acc[mi][ni][r] + bv, 0.f));
      }
    }
  }
}

// ---------------- fused GEMM + residual + LayerNorm ----------------
// SINGLE-buffered LDS (35KB) -> 4 blocks/CU (32 waves/CU): cross-block TLP
// covers the stage->compute serialization (R4 trade inverted).
template <bool WRITE_BF>
__launch_bounds__(512)
__global__ void gemmln_k(const unsigned short* __restrict__ A,
                         const unsigned short* __restrict__ Bt,
                         const float* __restrict__ bias,
                         const float* __restrict__ resid,
                         const float* __restrict__ lng,
                         const float* __restrict__ lnb,
                         float* __restrict__ outf,
                         unsigned short* __restrict__ outb,
                         int K)
{
  __shared__ alignas(16) unsigned short As[16 * 64];
  __shared__ alignas(16) unsigned short Bs[256 * 64];
  __shared__ float rsum[8][16], rsq[8][16], rmu[16], rrstd[16];
  const int tid  = threadIdx.x;
  const int lane = tid & 63, wv = tid >> 6;
  const int lr = lane & 15, g = lane >> 4;
  const int m0 = blockIdx.x * 16;
  const int l8 = lane >> 3, jj = lane & 7;

  f32x4 acc[2];
  acc[0] = (f32x4)(0.f); acc[1] = (f32x4)(0.f);

  for (int k0 = 0; k0 < K; k0 += 64) {
    // stage (single buffer)
    if (wv < 2) {
      const int row = wv * 8 + l8;
      GLL16(A + (size_t)(m0 + row) * K + k0 + ((jj ^ (row & 7)) * 8),
            &As[wv * 512]);
    }
#pragma unroll
    for (int i = 0; i < 4; ++i) {
      const int n = i * 64 + wv * 8 + l8;
      GLL16(Bt + (size_t)n * K + k0 + ((jj ^ (n & 7)) * 8),
            &Bs[i * 4096 + wv * 512]);
    }
    asm volatile("s_waitcnt vmcnt(0)" ::: "memory");
    __builtin_amdgcn_sched_barrier(0);
    __builtin_amdgcn_s_barrier();
#pragma unroll
    for (int kk = 0; kk < 2; ++kk) {
      FragU af, bf[2];
      {
        const int sw = (lr & 7) << 3;
        af.v = *(const short8*)&As[lr * 64 + ((kk * 32 + 8 * g) ^ sw)];
      }
#pragma unroll
      for (int ni = 0; ni < 2; ++ni) {
        const int row = wv * 32 + ni * 16 + lr;
        const int sw = (row & 7) << 3;
        bf[ni].v = *(const short8*)&Bs[row * 64 + ((kk * 32 + 8 * g) ^ sw)];
      }
#pragma unroll
      for (int ni = 0; ni < 2; ++ni)
        acc[ni] = __builtin_amdgcn_mfma_f32_16x16x32_bf16(af.v, bf[ni].v, acc[ni], 0, 0, 0);
    }
    // frag reads consumed by MFMA (register dependency) before this barrier
    asm volatile("s_waitcnt lgkmcnt(0)" ::: "memory");
    __builtin_amdgcn_sched_barrier(0);
    __builtin_amdgcn_s_barrier();
  }

  float g2[2], b2[2], bias2[2];
  int col[2];
#pragma unroll
  for (int ni = 0; ni < 2; ++ni) {
    col[ni] = wv * 32 + ni * 16 + lr;
    g2[ni] = lng[col[ni]]; b2[ni] = lnb[col[ni]]; bias2[ni] = bias[col[ni]];
  }
  float vals[2][4];
#pragma unroll
  for (int r = 0; r < 4; ++r) {
    const int row = 4 * g + r;
    float s = 0.f, q = 0.f;
#pragma unroll
    for (int ni = 0; ni < 2; ++ni) {
      float v = acc[ni][r] + bias2[ni] + resid[(size_t)(m0 + row) * D_ + col[ni]];
      vals[ni][r] = v; s += v; q += v * v;
    }
#pragma unroll
    for (int off = 1; off < 16; off <<= 1) {
      s += __shfl_xor(s, off); q += __shfl_xor(q, off);
    }
    if (lr == 0) { rsum[wv][row] = s; rsq[wv][row] = q; }
  }
  __syncthreads();
  if (tid < 16) {
    float s = 0.f, q = 0.f;
#pragma unroll
    for (int w = 0; w < 8; ++w) { s += rsum[w][tid]; q += rsq[w][tid]; }
    const float mu = s * (1.f / D_);
    rmu[tid] = mu;
    rrstd[tid] = rsqrtf(q * (1.f / D_) - mu * mu + 1e-5f);
  }
  __syncthreads();
#pragma unroll
  for (int r = 0; r < 4; ++r) {
    const int row = 4 * g + r;
    const float mu = rmu[row], rs = rrstd[row];
#pragma unroll
    for (int ni = 0; ni < 2; ++ni) {
      const float o = (vals[ni][r] - mu) * rs * g2[ni] + b2[ni];
      const size_t idx = (size_t)(m0 + row) * D_ + col[ni];
      outf[idx] = o;
      if constexpr (WRITE_BF) outb[idx] = f2bf(o);
    }
  }
}

// ---------------- flash attention (R16/R17 structure, unchanged) ----------------
__launch_bounds__(512)
__global__ void attn_k(const unsigned short* __restrict__ qb,
                       const unsigned short* __restrict__ kp,
                       const unsigned short* __restrict__ vT,
                       const float* __restrict__ maskf,
                       const float* __restrict__ mlo,
                       const float* __restrict__ mhi,
                       const float* __restrict__ relb,
                       unsigned short* __restrict__ aout)
{
  __shared__ alignas(16) unsigned short Ks[2][128 * 40];   // padded rows (80B)
  __shared__ alignas(16) unsigned short Vs[2][32 * 128];   // XOR-swizzled
  __shared__ alignas(16) float biasv[36];
  const int tid = threadIdx.x;
  const int lane = tid & 63, wv = tid >> 6;                // wv in 0..7
  const int lr = lane & 15, g = lane >> 4;
  // XCD-aware decode: 512 blocks = 8 xcd * 4 bh * 16 qblk (bijective)
  const int bid = blockIdx.x;
  const int ii = bid >> 3;
  const int bh = (bid & 7) * 4 + (ii >> 4);
  const int qblk = ii & 15;
  const int b = bh >> 3, h = bh & 7;
  const size_t bhoff = (size_t)bh * (L_ * DH_);
  if (tid < 33) biasv[tid] = relb[tid * H_ + h] * LOG2E;
  const int qw0 = qblk * 128 + wv * 16;

  FragU qf;
  qf.v = *(const short8*)(qb + bhoff + (size_t)(qw0 + lr) * DH_ + 8 * g);

  f32x4 O0 = (f32x4)(0.f), O1 = (f32x4)(0.f);
  f32x2 ssum2 = {0.f, 0.f};
  const f32x4 z4 = (f32x4)(0.f);
  const int krow = tid >> 2, koff = (tid & 3) * 8;         // 512 thr: 16B/thread
  const float* mtl = mlo + (size_t)bh * L_ + 4 * g;
  const float* mth = mhi + (size_t)bh * L_ + 4 * g;
  const float* mbn = maskf + (size_t)b * L_ + 4 * g;

  // prologue: stage chunk 0 into buffers[0]
  {
    const int4 ka = *(const int4*)(kp + bhoff + (size_t)krow * DH_ + koff);
    const int d = wv * 4 + (lane >> 4);
    GLL16(vT + ((size_t)bh * DH_ + d) * L_ + (((lane & 15) * 8) ^ ((d & 7) * 8)),
          &Vs[0][wv * 512]);
    *(int4*)&Ks[0][krow * 40 + koff] = ka;
    asm volatile("s_waitcnt vmcnt(0) lgkmcnt(0)" ::: "memory");
    __builtin_amdgcn_s_barrier();
  }

#pragma unroll 2
  for (int ch = 0; ch < 16; ++ch) {
    const int cur = ch & 1, nxt = cur ^ 1;
    const int kv = ch * 128;
    const bool more = ch < 15;
    int4 ka = {0, 0, 0, 0};
    if (more) {   // prefetch chunk ch+1: K->regs, V->LDS[nxt] via gll16
      ka = *(const int4*)(kp + bhoff + (size_t)(kv + 128 + krow) * DH_ + koff);
      const int d = wv * 4 + (lane >> 4);
      GLL16(vT + ((size_t)bh * DH_ + d) * L_ + kv + 128 + (((lane & 15) * 8) ^ ((d & 7) * 8)),
            &Vs[nxt][wv * 512]);
    }

    // hoisted QK phase: both sub-tiles' K frags (one b128 each) + 8 MFMAs
    SU sT[2][4];
#pragma unroll
    for (int st = 0; st < 2; ++st) {
      const unsigned short* KsC = &Ks[cur][st * 64 * 40];
#pragma unroll
      for (int jt = 0; jt < 4; ++jt) {
        FragU kf;
        kf.v = *(const short8*)&KsC[(jt * 16 + lr) * 40 + 8 * g];
        sT[st][jt].v4 = __builtin_amdgcn_mfma_f32_16x16x32_bf16(kf.v, qf.v, z4, 0, 0, 0);
      }
    }

#pragma unroll
    for (int st = 0; st < 2; ++st) {
      const int j0 = kv + st * 64;
      const int dlt = j0 - qw0;
      if (dlt >= 32 || dlt <= -80) {          // far field: pre-biased table
        const float* mt = (dlt > 0) ? mth : mtl;
#pragma unroll
        for (int jt = 0; jt < 4; ++jt) {
          SU mk; mk.v4 = *(const f32x4*)(mt + j0 + jt * 16);
          sT[st][jt].v2[0] = pk_add(sT[st][jt].v2[0], mk.v2[0]);
          sT[st][jt].v2[1] = pk_add(sT[st][jt].v2[1], mk.v2[1]);
        }
      } else {                                 // near field (2 of 32 sub-tiles)
#pragma unroll
        for (int jt = 0; jt < 4; ++jt)
#pragma unroll
          for (int r = 0; r < 4; ++r) {
            int rel = j0 + jt * 16 + 4 * g + r - (qw0 + lr);
            rel = rel < -16 ? -16 : (rel > 16 ? 16 : rel);
            sT[st][jt].v4[r] += biasv[rel + 16] + mbn[j0 + jt * 16 + r];
          }
      }
      // max-free: p = exp2(s) directly (masked -> 0)
#pragma unroll
      for (int jt = 0; jt < 4; ++jt)
#pragma unroll
        for (int r = 0; r < 4; ++r)
          sT[st][jt].v4[r] = fexp2(sT[st][jt].v4[r]);
      // packed partial-sum accumulate
      const f32x2 s01 = pk_add(sT[st][0].v2[0], sT[st][0].v2[1]);
      const f32x2 s23 = pk_add(sT[st][1].v2[0], sT[st][1].v2[1]);
      const f32x2 s45 = pk_add(sT[st][2].v2[0], sT[st][2].v2[1]);
      const f32x2 s67 = pk_add(sT[st][3].v2[0], sT[st][3].v2[1]);
      ssum2 = pk_add(ssum2, pk_add(pk_add(s01, s23), pk_add(s45, s67)));

      FragU a0, a1;
      a0.u[0] = cvt_pk_bf16(sT[st][0].v4[0], sT[st][0].v4[1]);
      a0.u[1] = cvt_pk_bf16(sT[st][0].v4[2], sT[st][0].v4[3]);
      a0.u[2] = cvt_pk_bf16(sT[st][1].v4[0], sT[st][1].v4[1]);
      a0.u[3] = cvt_pk_bf16(sT[st][1].v4[2], sT[st][1].v4[3]);
      a1.u[0] = cvt_pk_bf16(sT[st][2].v4[0], sT[st][2].v4[1]);
      a1.u[1] = cvt_pk_bf16(sT[st][2].v4[2], sT[st][2].v4[3]);
      a1.u[2] = cvt_pk_bf16(sT[st][3].v4[0], sT[st][3].v4[1]);
      a1.u[3] = cvt_pk_bf16(sT[st][3].v4[2], sT[st][3].v4[3]);

      FragU vf00, vf01, vf10, vf11;
#pragma unroll
      for (int dt = 0; dt < 2; ++dt) {
        const int row = dt * 16 + lr;
        const int sw = (row & 7) << 3;
        FragU v0, v1;
        v0.q.lo = *(const ull*)&Vs[cur][row * 128 + ((st * 64 + 4 * g) ^ sw)];
        v0.q.hi = *(const ull*)&Vs[cur][row * 128 + ((st * 64 + 16 + 4 * g) ^ sw)];
        v1.q.lo = *(const ull*)&Vs[cur][row * 128 + ((st * 64 + 32 + 4 * g) ^ sw)];
        v1.q.hi = *(const ull*)&Vs[cur][row * 128 + ((st * 64 + 48 + 4 * g) ^ sw)];
        if (dt == 0) { vf00 = v0; vf01 = v1; } else { vf10 = v0; vf11 = v1; }
      }
      O0 = __builtin_amdgcn_mfma_f32_16x16x32_bf16(a0.v, vf00.v, O0, 0, 0, 0);
      O0 = __builtin_amdgcn_mfma_f32_16x16x32_bf16(a1.v, vf01.v, O0, 0, 0, 0);
      O1 = __builtin_amdgcn_mfma_f32_16x16x32_bf16(a0.v, vf10.v, O1, 0, 0, 0);
      O1 = __builtin_amdgcn_mfma_f32_16x16x32_bf16(a1.v, vf11.v, O1, 0, 0, 0);
    }

    if (more) {  // write-late K into next buffer
      *(int4*)&Ks[nxt][krow * 40 + koff] = ka;
    }
    asm volatile("s_waitcnt vmcnt(0) lgkmcnt(0)" ::: "memory");
    __builtin_amdgcn_sched_barrier(0);
    __builtin_amdgcn_s_barrier();
  }

  // epilogue: reduce denominator, write O
  float ssum = ssum2[0] + ssum2[1];
  ssum += __shfl_xor(ssum, 16);
  ssum += __shfl_xor(ssum, 32);
#pragma unroll
  for (int r = 0; r < 4; ++r) {
    const float sden = __shfl(ssum, 4 * g + r);
    const float inv = 1.f / sden;
    const int qo = qw0 + 4 * g + r;
    unsigned short* orow = aout + ((size_t)(b * L_ + qo)) * D_ + h * DH_;
    orow[lr]      = f2bf(O0[r] * inv);
    orow[16 + lr] = f2bf(O1[r] * inv);
  }
}

// ---------------- launch ----------------
extern "C" void kernel_launch(void* const* d_in, const int* in_sizes, int n_in,
                              void* d_out, int out_size, void* d_ws, size_t ws_size,
                              hipStream_t stream) {
  (void)in_sizes; (void)n_in; (void)out_size; (void)ws_size;
  const float* x    = (const float*)d_in[0];
  const int*   mask = (const int*)d_in[1];
  const float* Wqkv = (const float*)d_in[2];
  const float* bqkv = (const float*)d_in[3];
  const float* Wo   = (const float*)d_in[4];
  const float* bo   = (const float*)d_in[5];
  const float* ln1g = (const float*)d_in[6];
  const float* ln1b = (const float*)d_in[7];
  const float* W1   = (const float*)d_in[8];
  const float* b1   = (const float*)d_in[9];
  const float* W2   = (const float*)d_in[10];
  const float* b2   = (const float*)d_in[11];
  const float* ln2g = (const float*)d_in[12];
  const float* ln2b = (const float*)d_in[13];
  const float* relb = (const float*)d_in[14];

  size_t off = 0;
  char* wsb = (char*)d_ws;
  auto carve = [&](size_t bytes) -> void* {
    void* p = wsb + off;
    off += (bytes + 255) & ~(size_t)255;
    return p;
  };
  const size_t tokb = (size_t)B_ * L_;
  unsigned short* xb    = (unsigned short*)carve(tokb * D_ * 2);
  unsigned short* qbuf  = (unsigned short*)carve(tokb * D_ * 2);
  unsigned short* kbuf  = (unsigned short*)carve(tokb * D_ * 2);
  unsigned short* vTb   = (unsigned short*)carve(tokb * D_ * 2);
  unsigned short* attnb = (unsigned short*)carve(tokb * D_ * 2);
  unsigned short* wqkvt = (unsigned short*)carve((size_t)3 * D_ * D_ * 2);
  unsigned short* wot   = (unsigned short*)carve((size_t)D_ * D_ * 2);
  unsigned short* w1t   = (unsigned short*)carve((size_t)D_ * MLP_ * 2);
  unsigned short* w2t   = (unsigned short*)carve((size_t)D_ * MLP_ * 2);
  float*          x1    = (float*)carve(tokb * D_ * 4);
  unsigned short* x1b   = (unsigned short*)carve(tokb * D_ * 2);
  unsigned short* hbuf  = (unsigned short*)carve(tokb * MLP_ * 2);
  float*          maskfb = (float*)carve(tokb * 4);
  float*          mlob  = (float*)carve((size_t)B_ * H_ * L_ * 4);
  float*          mhib  = (float*)carve((size_t)B_ * H_ * L_ * 4);

  prep_all<<<3360, 256, 0, stream>>>(x, mask, relb, Wqkv, Wo, W1, W2,
                                     xb, maskfb, mlob, mhib,
                                     wqkvt, wot, w1t, w2t);

  // qkv: nbx=6, nby=128 -> 768 blocks = 6*8*16
  gemm_k<0, 64, 128, 6, 16><<<768, 256, 0, stream>>>(
      xb, wqkvt, bqkv, qbuf, kbuf, vTb, D_);
  // attn: 512 blocks = 8 xcd * 4 bh * 16 qblk, 128 q/block
  attn_k<<<512, 512, 0, stream>>>(
      qbuf, kbuf, vTb, maskfb, mlob, mhib, relb, attnb);
  gemmln_k<true><<<tokb / 16, 512, 0, stream>>>(
      attnb, wot, bo, x, ln1g, ln1b, x1, x1b, D_);
  // mlp1: nbx=8, nby=128 -> 1024 blocks = 8*8*16
  gemm_k<2, 64, 128, 8, 16><<<1024, 256, 0, stream>>>(
      x1b, w1t, b1, hbuf, nullptr, nullptr, D_);
  gemmln_k<false><<<tokb / 16, 512, 0, stream>>>(
      hbuf, w2t, b2, x1, ln2g, ln2b, (float*)d_out, nullptr, MLP_);
}

// Round 19
// 94.903 us; speedup vs baseline: 1.3323x; 1.0110x over previous
//
#include <hip/hip_runtime.h>

#define B_   4
#define L_   2048
#define D_   256
#define H_   8
#define DH_  32
#define MLP_ 1024
#define LOG2E 1.4426950408889634f

typedef __attribute__((ext_vector_type(8))) short  short8;
typedef __attribute__((ext_vector_type(4))) float  f32x4;
typedef __attribute__((ext_vector_type(2))) float  f32x2;
typedef unsigned long long ull;

union FragU { short8 v; struct { ull lo, hi; } q; unsigned u[4]; };
union SU { f32x4 v4; f32x2 v2[2]; };

__device__ __forceinline__ unsigned short f2bf(float f) {
  unsigned u = __float_as_uint(f);
  u += 0x7fffu + ((u >> 16) & 1u);
  return (unsigned short)(u >> 16);
}

__device__ __forceinline__ float bf2f(unsigned short u) {
  return __uint_as_float((unsigned)u << 16);
}

__device__ __forceinline__ ull pack4(float a, float b, float c, float d) {
  return (ull)f2bf(a) | ((ull)f2bf(b) << 16) | ((ull)f2bf(c) << 32) | ((ull)f2bf(d) << 48);
}

__device__ __forceinline__ unsigned cvt_pk_bf16(float lo, float hi) {
  unsigned r;
  asm("v_cvt_pk_bf16_f32 %0, %1, %2" : "=v"(r) : "v"(lo), "v"(hi));
  return r;
}

// packed f32 add (legal VOP3P on gfx950; pk_max is NOT)
__device__ __forceinline__ f32x2 pk_add(f32x2 a, f32x2 b) {
  f32x2 r; asm("v_pk_add_f32 %0, %1, %2" : "=v"(r) : "v"(a), "v"(b)); return r;
}

__device__ __forceinline__ float fexp2(float x) {
#if __has_builtin(__builtin_amdgcn_exp2f)
  return __builtin_amdgcn_exp2f(x);
#else
  return exp2f(x);
#endif
}

#define GLL16(gp, lp) __builtin_amdgcn_global_load_lds( \
    (const __attribute__((address_space(1))) void*)(gp), \
    (__attribute__((address_space(3))) void*)(lp), 16, 0, 0)

// ---------------- all input prep, ONE launch ----------------
__launch_bounds__(256)
__global__ void prep_all(const float* __restrict__ x,
                         const int* __restrict__ mask, const float* __restrict__ relb,
                         const float* __restrict__ Wqkv, const float* __restrict__ Wo,
                         const float* __restrict__ W1, const float* __restrict__ W2,
                         unsigned short* __restrict__ xb,
                         float* __restrict__ maskf,
                         float* __restrict__ mlo, float* __restrict__ mhi,
                         unsigned short* __restrict__ wqkvt, unsigned short* __restrict__ wot,
                         unsigned short* __restrict__ w1t, unsigned short* __restrict__ w2t) {
  __shared__ float tile[32][33];
  const int bid = blockIdx.x;
  if (bid < 768) {
    const float* src; unsigned short* dst; int R, C, tr, tc;
    if (bid < 192)      { src = Wqkv; dst = wqkvt; R = 256;  C = 768;  tr = bid / 24;          tc = bid % 24; }
    else if (bid < 256) { src = Wo;   dst = wot;   R = 256;  C = 256;  tr = (bid - 192) >> 3;  tc = (bid - 192) & 7; }
    else if (bid < 512) { src = W1;   dst = w1t;   R = 256;  C = 1024; tr = (bid - 256) >> 5;  tc = (bid - 256) & 31; }
    else                { src = W2;   dst = w2t;   R = 1024; C = 256;  tr = (bid - 512) >> 3;  tc = (bid - 512) & 7; }
    const int tx = threadIdx.x & 31, ty = threadIdx.x >> 5;
#pragma unroll
    for (int i = 0; i < 4; ++i) {
      const int r = tr * 32 + ty + i * 8;
      tile[ty + i * 8][tx] = src[(size_t)r * C + tc * 32 + tx];
    }
    __syncthreads();
#pragma unroll
    for (int i = 0; i < 4; ++i) {
      const int c = tc * 32 + ty + i * 8;
      dst[(size_t)c * R + tr * 32 + tx] = f2bf(tile[tx][ty + i * 8]);
    }
  } else {
    const int i = (bid - 768) * 256 + threadIdx.x;
    if (i < 524288) {            // x: 2,097,152 floats, 4 per thread
      const float4 v = *(const float4*)(x + (size_t)i * 4);
      *(ull*)(xb + (size_t)i * 4) = pack4(v.x, v.y, v.z, v.w);
    } else if (i < 532480) {     // raw mask -> additive float [B,L]
      const int j = i - 524288;
      maskf[j] = mask[j] ? -1e9f : 0.f;
    } else {                     // pre-biased far-field tables [B*H][L], lo and hi
      const int j2 = i - 532480;
      const int t = j2 >> 16, idx = j2 & 65535;
      const int bh = idx >> 11, j = idx & 2047;
      const int bq = bh >> 3, h = bh & 7;
      const float base = mask[bq * L_ + j] ? -1e9f : 0.f;
      const float bias = relb[(t ? 32 * H_ : 0) + h] * LOG2E;
      (t ? mhi : mlo)[idx] = base + bias;
    }
  }
}

// ---------------- GEMM (dbuf, counted vmcnt, XCD-swizzled 1D grid) ----------------
template <int MODE, int TM, int TN, int NBX, int BYG>
__launch_bounds__(256)
__global__ void gemm_k(const unsigned short* __restrict__ A,
                       const unsigned short* __restrict__ Bt,
                       const float* __restrict__ bias,
                       unsigned short* __restrict__ outb0,
                       unsigned short* __restrict__ outb1,
                       unsigned short* __restrict__ outb2,
                       int K)
{
  constexpr int MI = TM / 32, NI = TN / 32;
  __shared__ alignas(16) unsigned short As[2][TM * 64];
  __shared__ alignas(16) unsigned short Bs[2][TN * 64];
  const int tid  = threadIdx.x;
  const int lane = tid & 63, wv = tid >> 6;
  const int wr = wv >> 1, wc = wv & 1;
  const int lr = lane & 15, g = lane >> 4;
  const int bid = blockIdx.x;
  const int xcd = bid & 7, ii = bid >> 3;
  const int by = xcd * BYG + ii / NBX;
  const int bx = ii % NBX;
  const int m0 = by * TM, n0 = bx * TN;
  const int l8 = lane >> 3, jj = lane & 7;

  auto stage = [&](int buf, int k0) {
#pragma unroll
    for (int i = 0; i < MI; ++i) {
      const int row = i * 32 + wv * 8 + l8;
      GLL16(A + (size_t)(m0 + row) * K + k0 + ((jj ^ (row & 7)) * 8),
            &As[buf][i * 2048 + wv * 512]);
    }
#pragma unroll
    for (int i = 0; i < NI; ++i) {
      const int row = i * 32 + wv * 8 + l8;
      GLL16(Bt + (size_t)(n0 + row) * K + k0 + ((jj ^ (row & 7)) * 8),
            &Bs[buf][i * 2048 + wv * 512]);
    }
  };

  f32x4 acc[MI][NI];
#pragma unroll
  for (int i = 0; i < MI; ++i)
#pragma unroll
    for (int j = 0; j < NI; ++j) acc[i][j] = (f32x4)(0.f);

  stage(0, 0);
  for (int k0 = 0; k0 < K; k0 += 64) {
    const int cur = (k0 >> 6) & 1;
    if (k0 + 64 < K) {
      stage(cur ^ 1, k0 + 64);
      asm volatile("s_waitcnt vmcnt(%0)" :: "n"(MI + NI) : "memory");
    } else {
      asm volatile("s_waitcnt vmcnt(0)" ::: "memory");
    }
    __builtin_amdgcn_sched_barrier(0);
    __builtin_amdgcn_s_barrier();
#pragma unroll
    for (int kk = 0; kk < 2; ++kk) {
      FragU af[MI], bf[NI];
#pragma unroll
      for (int mi = 0; mi < MI; ++mi) {
        const int row = wr * (TM / 2) + mi * 16 + lr;
        const int sw = (row & 7) << 3;
        af[mi].v = *(const short8*)&As[cur][row * 64 + ((kk * 32 + 8 * g) ^ sw)];
      }
#pragma unroll
      for (int ni = 0; ni < NI; ++ni) {
        const int row = wc * (TN / 2) + ni * 16 + lr;
        const int sw = (row & 7) << 3;
        bf[ni].v = *(const short8*)&Bs[cur][row * 64 + ((kk * 32 + 8 * g) ^ sw)];
      }
#pragma unroll
      for (int mi = 0; mi < MI; ++mi)
#pragma unroll
        for (int ni = 0; ni < NI; ++ni)
          acc[mi][ni] = __builtin_amdgcn_mfma_f32_16x16x32_bf16(af[mi].v, bf[ni].v, acc[mi][ni], 0, 0, 0);
    }
    asm volatile("s_waitcnt lgkmcnt(0)" ::: "memory");
    __builtin_amdgcn_sched_barrier(0);
    __builtin_amdgcn_s_barrier();
  }

#pragma unroll
  for (int mi = 0; mi < MI; ++mi) {
#pragma unroll
    for (int ni = 0; ni < NI; ++ni) {
      const int n = n0 + wc * (TN / 2) + ni * 16 + lr;
      const float bv = bias[n];
      const int mrow = m0 + wr * (TM / 2) + mi * 16 + 4 * g;
      if constexpr (MODE == 0) {
        const int s = n >> 8, hh = (n >> 5) & 7, dh = n & 31;
        const int bb = m0 >> 11;                 // TM=64 tile never crosses a batch
        if (s == 2) {                            // vT: 4 consecutive l -> one 8B store
          const int l0 = mrow & (L_ - 1);
          *(ull*)&outb2[((size_t)(bb * H_ + hh) * DH_ + dh) * L_ + l0] =
              pack4(acc[mi][ni][0] + bv, acc[mi][ni][1] + bv,
                    acc[mi][ni][2] + bv, acc[mi][ni][3] + bv);
        } else {
#pragma unroll
          for (int r = 0; r < 4; ++r) {
            const int l = (mrow + r) & (L_ - 1);
            const float val = acc[mi][ni][r] + bv;
            if (s == 0)
              outb0[((size_t)(bb * H_ + hh) * L_ + l) * DH_ + dh] =
                  f2bf(val * (0.17677669529663687f * LOG2E));
            else
              outb1[((size_t)(bb * H_ + hh) * L_ + l) * DH_ + dh] = f2bf(val);
          }
        }
      } else {
#pragma unroll
        for (int r = 0; r < 4; ++r)
          outb0[(size_t)(mrow + r) * MLP_ + n] = f2bf(fmaxf(acc[mi][ni][r] + bv, 0.f));
      }
    }
  }
}

// ---------------- fused GEMM + residual + LayerNorm (single-buffer LDS) ----------------
// RESID_BF: residual read as bf16 (mlp2 path); else fp32 (proj path reads x).
// WRITE_F: write fp32 out (d_out); WRITE_BF: write bf16 out (x1b).
template <bool WRITE_F, bool WRITE_BF, bool RESID_BF>
__launch_bounds__(512)
__global__ void gemmln_k(const unsigned short* __restrict__ A,
                         const unsigned short* __restrict__ Bt,
                         const float* __restrict__ bias,
                         const void* __restrict__ resid,
                         const float* __restrict__ lng,
                         const float* __restrict__ lnb,
                         float* __restrict__ outf,
                         unsigned short* __restrict__ outb,
                         int K)
{
  __shared__ alignas(16) unsigned short As[16 * 64];
  __shared__ alignas(16) unsigned short Bs[256 * 64];
  __shared__ float rsum[8][16], rsq[8][16], rmu[16], rrstd[16];
  const int tid  = threadIdx.x;
  const int lane = tid & 63, wv = tid >> 6;
  const int lr = lane & 15, g = lane >> 4;
  const int m0 = blockIdx.x * 16;
  const int l8 = lane >> 3, jj = lane & 7;

  f32x4 acc[2];
  acc[0] = (f32x4)(0.f); acc[1] = (f32x4)(0.f);

  for (int k0 = 0; k0 < K; k0 += 64) {
    if (wv < 2) {
      const int row = wv * 8 + l8;
      GLL16(A + (size_t)(m0 + row) * K + k0 + ((jj ^ (row & 7)) * 8),
            &As[wv * 512]);
    }
#pragma unroll
    for (int i = 0; i < 4; ++i) {
      const int n = i * 64 + wv * 8 + l8;
      GLL16(Bt + (size_t)n * K + k0 + ((jj ^ (n & 7)) * 8),
            &Bs[i * 4096 + wv * 512]);
    }
    asm volatile("s_waitcnt vmcnt(0)" ::: "memory");
    __builtin_amdgcn_sched_barrier(0);
    __builtin_amdgcn_s_barrier();
#pragma unroll
    for (int kk = 0; kk < 2; ++kk) {
      FragU af, bf[2];
      {
        const int sw = (lr & 7) << 3;
        af.v = *(const short8*)&As[lr * 64 + ((kk * 32 + 8 * g) ^ sw)];
      }
#pragma unroll
      for (int ni = 0; ni < 2; ++ni) {
        const int row = wv * 32 + ni * 16 + lr;
        const int sw = (row & 7) << 3;
        bf[ni].v = *(const short8*)&Bs[row * 64 + ((kk * 32 + 8 * g) ^ sw)];
      }
#pragma unroll
      for (int ni = 0; ni < 2; ++ni)
        acc[ni] = __builtin_amdgcn_mfma_f32_16x16x32_bf16(af.v, bf[ni].v, acc[ni], 0, 0, 0);
    }
    asm volatile("s_waitcnt lgkmcnt(0)" ::: "memory");
    __builtin_amdgcn_sched_barrier(0);
    __builtin_amdgcn_s_barrier();
  }

  float g2[2], b2[2], bias2[2];
  int col[2];
#pragma unroll
  for (int ni = 0; ni < 2; ++ni) {
    col[ni] = wv * 32 + ni * 16 + lr;
    g2[ni] = lng[col[ni]]; b2[ni] = lnb[col[ni]]; bias2[ni] = bias[col[ni]];
  }
  float vals[2][4];
#pragma unroll
  for (int r = 0; r < 4; ++r) {
    const int row = 4 * g + r;
    float s = 0.f, q = 0.f;
#pragma unroll
    for (int ni = 0; ni < 2; ++ni) {
      const size_t idx = (size_t)(m0 + row) * D_ + col[ni];
      const float rv = RESID_BF ? bf2f(((const unsigned short*)resid)[idx])
                                : ((const float*)resid)[idx];
      float v = acc[ni][r] + bias2[ni] + rv;
      vals[ni][r] = v; s += v; q += v * v;
    }
#pragma unroll
    for (int off = 1; off < 16; off <<= 1) {
      s += __shfl_xor(s, off); q += __shfl_xor(q, off);
    }
    if (lr == 0) { rsum[wv][row] = s; rsq[wv][row] = q; }
  }
  __syncthreads();
  if (tid < 16) {
    float s = 0.f, q = 0.f;
#pragma unroll
    for (int w = 0; w < 8; ++w) { s += rsum[w][tid]; q += rsq[w][tid]; }
    const float mu = s * (1.f / D_);
    rmu[tid] = mu;
    rrstd[tid] = rsqrtf(q * (1.f / D_) - mu * mu + 1e-5f);
  }
  __syncthreads();
#pragma unroll
  for (int r = 0; r < 4; ++r) {
    const int row = 4 * g + r;
    const float mu = rmu[row], rs = rrstd[row];
#pragma unroll
    for (int ni = 0; ni < 2; ++ni) {
      const float o = (vals[ni][r] - mu) * rs * g2[ni] + b2[ni];
      const size_t idx = (size_t)(m0 + row) * D_ + col[ni];
      if constexpr (WRITE_F)  outf[idx] = o;
      if constexpr (WRITE_BF) outb[idx] = f2bf(o);
    }
  }
}

// ---------------- flash attention (R16-R18 structure, unchanged) ----------------
__launch_bounds__(512)
__global__ void attn_k(const unsigned short* __restrict__ qb,
                       const unsigned short* __restrict__ kp,
                       const unsigned short* __restrict__ vT,
                       const float* __restrict__ maskf,
                       const float* __restrict__ mlo,
                       const float* __restrict__ mhi,
                       const float* __restrict__ relb,
                       unsigned short* __restrict__ aout)
{
  __shared__ alignas(16) unsigned short Ks[2][128 * 40];   // padded rows (80B)
  __shared__ alignas(16) unsigned short Vs[2][32 * 128];   // XOR-swizzled
  __shared__ alignas(16) float biasv[36];
  const int tid = threadIdx.x;
  const int lane = tid & 63, wv = tid >> 6;                // wv in 0..7
  const int lr = lane & 15, g = lane >> 4;
  // XCD-aware decode: 512 blocks = 8 xcd * 4 bh * 16 qblk (bijective)
  const int bid = blockIdx.x;
  const int ii = bid >> 3;
  const int bh = (bid & 7) * 4 + (ii >> 4);
  const int qblk = ii & 15;
  const int b = bh >> 3, h = bh & 7;
  const size_t bhoff = (size_t)bh * (L_ * DH_);
  if (tid < 33) biasv[tid] = relb[tid * H_ + h] * LOG2E;
  const int qw0 = qblk * 128 + wv * 16;

  FragU qf;
  qf.v = *(const short8*)(qb + bhoff + (size_t)(qw0 + lr) * DH_ + 8 * g);

  f32x4 O0 = (f32x4)(0.f), O1 = (f32x4)(0.f);
  f32x2 ssum2 = {0.f, 0.f};
  const f32x4 z4 = (f32x4)(0.f);
  const int krow = tid >> 2, koff = (tid & 3) * 8;         // 512 thr: 16B/thread
  const float* mtl = mlo + (size_t)bh * L_ + 4 * g;
  const float* mth = mhi + (size_t)bh * L_ + 4 * g;
  const float* mbn = maskf + (size_t)b * L_ + 4 * g;

  // prologue: stage chunk 0 into buffers[0]
  {
    const int4 ka = *(const int4*)(kp + bhoff + (size_t)krow * DH_ + koff);
    const int d = wv * 4 + (lane >> 4);
    GLL16(vT + ((size_t)bh * DH_ + d) * L_ + (((lane & 15) * 8) ^ ((d & 7) * 8)),
          &Vs[0][wv * 512]);
    *(int4*)&Ks[0][krow * 40 + koff] = ka;
    asm volatile("s_waitcnt vmcnt(0) lgkmcnt(0)" ::: "memory");
    __builtin_amdgcn_s_barrier();
  }

#pragma unroll 2
  for (int ch = 0; ch < 16; ++ch) {
    const int cur = ch & 1, nxt = cur ^ 1;
    const int kv = ch * 128;
    const bool more = ch < 15;
    int4 ka = {0, 0, 0, 0};
    if (more) {   // prefetch chunk ch+1: K->regs, V->LDS[nxt] via gll16
      ka = *(const int4*)(kp + bhoff + (size_t)(kv + 128 + krow) * DH_ + koff);
      const int d = wv * 4 + (lane >> 4);
      GLL16(vT + ((size_t)bh * DH_ + d) * L_ + kv + 128 + (((lane & 15) * 8) ^ ((d & 7) * 8)),
            &Vs[nxt][wv * 512]);
    }

    // hoisted QK phase: both sub-tiles' K frags (one b128 each) + 8 MFMAs
    SU sT[2][4];
#pragma unroll
    for (int st = 0; st < 2; ++st) {
      const unsigned short* KsC = &Ks[cur][st * 64 * 40];
#pragma unroll
      for (int jt = 0; jt < 4; ++jt) {
        FragU kf;
        kf.v = *(const short8*)&KsC[(jt * 16 + lr) * 40 + 8 * g];
        sT[st][jt].v4 = __builtin_amdgcn_mfma_f32_16x16x32_bf16(kf.v, qf.v, z4, 0, 0, 0);
      }
    }

#pragma unroll
    for (int st = 0; st < 2; ++st) {
      const int j0 = kv + st * 64;
      const int dlt = j0 - qw0;
      if (dlt >= 32 || dlt <= -80) {          // far field: pre-biased table
        const float* mt = (dlt > 0) ? mth : mtl;
#pragma unroll
        for (int jt = 0; jt < 4; ++jt) {
          SU mk; mk.v4 = *(const f32x4*)(mt + j0 + jt * 16);
          sT[st][jt].v2[0] = pk_add(sT[st][jt].v2[0], mk.v2[0]);
          sT[st][jt].v2[1] = pk_add(sT[st][jt].v2[1], mk.v2[1]);
        }
      } else {                                 // near field (2 of 32 sub-tiles)
#pragma unroll
        for (int jt = 0; jt < 4; ++jt)
#pragma unroll
          for (int r = 0; r < 4; ++r) {
            int rel = j0 + jt * 16 + 4 * g + r - (qw0 + lr);
            rel = rel < -16 ? -16 : (rel > 16 ? 16 : rel);
            sT[st][jt].v4[r] += biasv[rel + 16] + mbn[j0 + jt * 16 + r];
          }
      }
      // max-free: p = exp2(s) directly (masked -> 0)
#pragma unroll
      for (int jt = 0; jt < 4; ++jt)
#pragma unroll
        for (int r = 0; r < 4; ++r)
          sT[st][jt].v4[r] = fexp2(sT[st][jt].v4[r]);
      // packed partial-sum accumulate
      const f32x2 s01 = pk_add(sT[st][0].v2[0], sT[st][0].v2[1]);
      const f32x2 s23 = pk_add(sT[st][1].v2[0], sT[st][1].v2[1]);
      const f32x2 s45 = pk_add(sT[st][2].v2[0], sT[st][2].v2[1]);
      const f32x2 s67 = pk_add(sT[st][3].v2[0], sT[st][3].v2[1]);
      ssum2 = pk_add(ssum2, pk_add(pk_add(s01, s23), pk_add(s45, s67)));

      FragU a0, a1;
      a0.u[0] = cvt_pk_bf16(sT[st][0].v4[0], sT[st][0].v4[1]);
      a0.u[1] = cvt_pk_bf16(sT[st][0].v4[2], sT[st][0].v4[3]);
      a0.u[2] = cvt_pk_bf16(sT[st][1].v4[0], sT[st][1].v4[1]);
      a0.u[3] = cvt_pk_bf16(sT[st][1].v4[2], sT[st][1].v4[3]);
      a1.u[0] = cvt_pk_bf16(sT[st][2].v4[0], sT[st][2].v4[1]);
      a1.u[1] = cvt_pk_bf16(sT[st][2].v4[2], sT[st][2].v4[3]);
      a1.u[2] = cvt_pk_bf16(sT[st][3].v4[0], sT[st][3].v4[1]);
      a1.u[3] = cvt_pk_bf16(sT[st][3].v4[2], sT[st][3].v4[3]);

      FragU vf00, vf01, vf10, vf11;
#pragma unroll
      for (int dt = 0; dt < 2; ++dt) {
        const int row = dt * 16 + lr;
        const int sw = (row & 7) << 3;
        FragU v0, v1;
        v0.q.lo = *(const ull*)&Vs[cur][row * 128 + ((st * 64 + 4 * g) ^ sw)];
        v0.q.hi = *(const ull*)&Vs[cur][row * 128 + ((st * 64 + 16 + 4 * g) ^ sw)];
        v1.q.lo = *(const ull*)&Vs[cur][row * 128 + ((st * 64 + 32 + 4 * g) ^ sw)];
        v1.q.hi = *(const ull*)&Vs[cur][row * 128 + ((st * 64 + 48 + 4 * g) ^ sw)];
        if (dt == 0) { vf00 = v0; vf01 = v1; } else { vf10 = v0; vf11 = v1; }
      }
      O0 = __builtin_amdgcn_mfma_f32_16x16x32_bf16(a0.v, vf00.v, O0, 0, 0, 0);
      O0 = __builtin_amdgcn_mfma_f32_16x16x32_bf16(a1.v, vf01.v, O0, 0, 0, 0);
      O1 = __builtin_amdgcn_mfma_f32_16x16x32_bf16(a0.v, vf10.v, O1, 0, 0, 0);
      O1 = __builtin_amdgcn_mfma_f32_16x16x32_bf16(a1.v, vf11.v, O1, 0, 0, 0);
    }

    if (more) {  // write-late K into next buffer
      *(int4*)&Ks[nxt][krow * 40 + koff] = ka;
    }
    asm volatile("s_waitcnt vmcnt(0) lgkmcnt(0)" ::: "memory");
    __builtin_amdgcn_sched_barrier(0);
    __builtin_amdgcn_s_barrier();
  }

  // epilogue: reduce denominator, write O
  float ssum = ssum2[0] + ssum2[1];
  ssum += __shfl_xor(ssum, 16);
  ssum += __shfl_xor(ssum, 32);
#pragma unroll
  for (int r = 0; r < 4; ++r) {
    const float sden = __shfl(ssum, 4 * g + r);
    const float inv = 1.f / sden;
    const int qo = qw0 + 4 * g + r;
    unsigned short* orow = aout + ((size_t)(b * L_ + qo)) * D_ + h * DH_;
    orow[lr]      = f2bf(O0[r] * inv);
    orow[16 + lr] = f2bf(O1[r] * inv);
  }
}

// ---------------- launch ----------------
extern "C" void kernel_launch(void* const* d_in, const int* in_sizes, int n_in,
                              void* d_out, int out_size, void* d_ws, size_t ws_size,
                              hipStream_t stream) {
  (void)in_sizes; (void)n_in; (void)out_size; (void)ws_size;
  const float* x    = (const float*)d_in[0];
  const int*   mask = (const int*)d_in[1];
  const float* Wqkv = (const float*)d_in[2];
  const float* bqkv = (const float*)d_in[3];
  const float* Wo   = (const float*)d_in[4];
  const float* bo   = (const float*)d_in[5];
  const float* ln1g = (const float*)d_in[6];
  const float* ln1b = (const float*)d_in[7];
  const float* W1   = (const float*)d_in[8];
  const float* b1   = (const float*)d_in[9];
  const float* W2   = (const float*)d_in[10];
  const float* b2   = (const float*)d_in[11];
  const float* ln2g = (const float*)d_in[12];
  const float* ln2b = (const float*)d_in[13];
  const float* relb = (const float*)d_in[14];

  size_t off = 0;
  char* wsb = (char*)d_ws;
  auto carve = [&](size_t bytes) -> void* {
    void* p = wsb + off;
    off += (bytes + 255) & ~(size_t)255;
    return p;
  };
  const size_t tokb = (size_t)B_ * L_;
  unsigned short* xb    = (unsigned short*)carve(tokb * D_ * 2);
  unsigned short* qbuf  = (unsigned short*)carve(tokb * D_ * 2);
  unsigned short* kbuf  = (unsigned short*)carve(tokb * D_ * 2);
  unsigned short* vTb   = (unsigned short*)carve(tokb * D_ * 2);
  unsigned short* attnb = (unsigned short*)carve(tokb * D_ * 2);
  unsigned short* wqkvt = (unsigned short*)carve((size_t)3 * D_ * D_ * 2);
  unsigned short* wot   = (unsigned short*)carve((size_t)D_ * D_ * 2);
  unsigned short* w1t   = (unsigned short*)carve((size_t)D_ * MLP_ * 2);
  unsigned short* w2t   = (unsigned short*)carve((size_t)D_ * MLP_ * 2);
  unsigned short* x1b   = (unsigned short*)carve(tokb * D_ * 2);
  unsigned short* hbuf  = (unsigned short*)carve(tokb * MLP_ * 2);
  float*          maskfb = (float*)carve(tokb * 4);
  float*          mlob  = (float*)carve((size_t)B_ * H_ * L_ * 4);
  float*          mhib  = (float*)carve((size_t)B_ * H_ * L_ * 4);

  prep_all<<<3360, 256, 0, stream>>>(x, mask, relb, Wqkv, Wo, W1, W2,
                                     xb, maskfb, mlob, mhib,
                                     wqkvt, wot, w1t, w2t);

  // qkv: nbx=6, nby=128 -> 768 blocks = 6*8*16
  gemm_k<0, 64, 128, 6, 16><<<768, 256, 0, stream>>>(
      xb, wqkvt, bqkv, qbuf, kbuf, vTb, D_);
  // attn: 512 blocks = 8 xcd * 4 bh * 16 qblk, 128 q/block
  attn_k<<<512, 512, 0, stream>>>(
      qbuf, kbuf, vTb, maskfb, mlob, mhib, relb, attnb);
  // proj + LN1: resid = x (fp32), write ONLY bf16 x1b
  gemmln_k<false, true, false><<<tokb / 16, 512, 0, stream>>>(
      attnb, wot, bo, x, ln1g, ln1b, nullptr, x1b, D_);
  // mlp1: nbx=8, nby=128 -> 1024 blocks = 8*8*16
  gemm_k<2, 64, 128, 8, 16><<<1024, 256, 0, stream>>>(
      x1b, w1t, b1, hbuf, nullptr, nullptr, D_);
  // mlp2 + LN2: resid = x1b (bf16), write fp32 d_out
  gemmln_k<true, false, true><<<tokb / 16, 512, 0, stream>>>(
      hbuf, w2t, b2, x1b, ln2g, ln2b, (float*)d_out, nullptr, MLP_);
}